// Round 1
// baseline (1843.018 us; speedup 1.0000x reference)
//
#include <hip/hip_runtime.h>

// GIN: 2 x (scatter-sum + MLP(64->64->64) + BatchNorm + ReLU) + global mean pool
// N=50000 nodes, E=800000 edges, H=64, G=16 graphs. All fp32.

constexpr int NN = 50000;
constexpr int NE = 800000;
constexpr int HD = 64;
constexpr int NG = 16;
constexpr float BN_EPS = 1e-5f;

// ---------------------------------------------------------------------------
// Scatter: agg[dst] += x[src] over all edges. One thread per (edge, 4-feat
// chunk): coalesced float4 gather of x row (L2/L3-resident table), 4 float
// atomicAdds into agg.
// ---------------------------------------------------------------------------
__global__ __launch_bounds__(256)
void scatter_kernel(const float* __restrict__ x, const int* __restrict__ ei,
                    float* __restrict__ agg) {
    long tid = (long)blockIdx.x * blockDim.x + threadIdx.x;
    if (tid >= (long)NE * 16) return;
    int e = (int)(tid >> 4);
    int c = ((int)tid & 15) << 2;
    int src = ei[e];
    int dst = ei[NE + e];
    float4 v = *(const float4*)(x + (size_t)src * HD + c);
    float* o = agg + (size_t)dst * HD + c;
    atomicAdd(o + 0, v.x);
    atomicAdd(o + 1, v.y);
    atomicAdd(o + 2, v.z);
    atomicAdd(o + 3, v.w);
}

// ---------------------------------------------------------------------------
// Fused MLP: h2 = ReLU((x+agg) @ W1 + b1) @ W2 + b2, written in-place over agg.
// Thread-per-row; W1/W2 in LDS (broadcast reads); all register-array indices
// static. Chunked over 8 t-columns at a time so GEMM2 can consume t while its
// index is still a compile-time constant (avoids scratch).
// ---------------------------------------------------------------------------
__global__ __launch_bounds__(256)
void mlp_kernel(const float* __restrict__ x, float* __restrict__ h,
                const float* __restrict__ W1, const float* __restrict__ b1,
                const float* __restrict__ W2, const float* __restrict__ b2) {
    __shared__ float sW1[64 * 64];
    __shared__ float sW2[64 * 64];
    __shared__ float sb1[64];
    __shared__ float sb2[64];
    for (int i = threadIdx.x; i < 4096; i += 256) {
        sW1[i] = W1[i];
        sW2[i] = W2[i];
    }
    if (threadIdx.x < 64) {
        sb1[threadIdx.x] = b1[threadIdx.x];
        sb2[threadIdx.x] = b2[threadIdx.x];
    }
    __syncthreads();
    int row = blockIdx.x * 256 + threadIdx.x;
    if (row >= NN) return;

    float hv[64];
    {
        const float4* xr = (const float4*)(x + (size_t)row * HD);
        const float4* ar = (const float4*)(h + (size_t)row * HD);
#pragma unroll
        for (int i = 0; i < 16; i++) {
            float4 a = xr[i], b = ar[i];
            hv[4 * i + 0] = a.x + b.x;
            hv[4 * i + 1] = a.y + b.y;
            hv[4 * i + 2] = a.z + b.z;
            hv[4 * i + 3] = a.w + b.w;
        }
    }

    float acc[64];
#pragma unroll
    for (int j = 0; j < 64; j++) acc[j] = sb2[j];

#pragma unroll 1  // keep body ~1K FMAs: fits I-cache, reg indices stay static
    for (int c = 0; c < 8; c++) {
        float t[8];
#pragma unroll
        for (int i = 0; i < 8; i++) t[i] = sb1[c * 8 + i];
        const float* w1c = sW1 + c * 8;
#pragma unroll
        for (int k = 0; k < 64; k++) {
            float a = hv[k];
#pragma unroll
            for (int i = 0; i < 8; i++) t[i] += a * w1c[k * 64 + i];
        }
#pragma unroll
        for (int i = 0; i < 8; i++) t[i] = fmaxf(t[i], 0.f);
        const float* w2c = sW2 + c * 8 * 64;
#pragma unroll
        for (int i = 0; i < 8; i++) {
            float a = t[i];
#pragma unroll
            for (int j = 0; j < 64; j++) acc[j] += a * w2c[i * 64 + j];
        }
    }

    float4* hr = (float4*)(h + (size_t)row * HD);
#pragma unroll
    for (int i = 0; i < 16; i++)
        hr[i] = make_float4(acc[4 * i], acc[4 * i + 1], acc[4 * i + 2], acc[4 * i + 3]);
}

// ---------------------------------------------------------------------------
// Column sum / sumsq over all N rows (for BatchNorm batch stats).
// ---------------------------------------------------------------------------
__global__ __launch_bounds__(256)
void stats_kernel(const float* __restrict__ h, float* __restrict__ stats) {
    int col = threadIdx.x & 63;
    int rl = threadIdx.x >> 6;
    float s = 0.f, ss = 0.f;
    for (int r = blockIdx.x * 4 + rl; r < NN; r += gridDim.x * 4) {
        float v = h[(size_t)r * HD + col];
        s += v;
        ss += v * v;
    }
    __shared__ float red[2][4][64];
    red[0][rl][col] = s;
    red[1][rl][col] = ss;
    __syncthreads();
    if (rl == 0) {
        s = red[0][0][col] + red[0][1][col] + red[0][2][col] + red[0][3][col];
        ss = red[1][0][col] + red[1][1][col] + red[1][2][col] + red[1][3][col];
        atomicAdd(stats + col, s);
        atomicAdd(stats + 64 + col, ss);
    }
}

// ---------------------------------------------------------------------------
// BatchNorm (training-mode batch stats, biased var) + affine + ReLU.
// ---------------------------------------------------------------------------
__global__ __launch_bounds__(256)
void norm_kernel(const float* __restrict__ h, const float* __restrict__ stats,
                 const float* __restrict__ g, const float* __restrict__ be,
                 float* __restrict__ out) {
    size_t i4 = (size_t)blockIdx.x * 256 + threadIdx.x;
    if (i4 >= (size_t)NN * HD / 4) return;
    size_t off = i4 * 4;
    int col = (int)(off & 63);
    float4 v = *(const float4*)(h + off);
    float4 sm = *(const float4*)(stats + col);
    float4 sq = *(const float4*)(stats + 64 + col);
    float4 gg = *(const float4*)(g + col);
    float4 bb = *(const float4*)(be + col);
    const float inv = 1.f / (float)NN;
    float4 o;
    {
        float mu = sm.x * inv, var = sq.x * inv - mu * mu;
        float sc = gg.x * rsqrtf(var + BN_EPS);
        o.x = fmaxf((v.x - mu) * sc + bb.x, 0.f);
    }
    {
        float mu = sm.y * inv, var = sq.y * inv - mu * mu;
        float sc = gg.y * rsqrtf(var + BN_EPS);
        o.y = fmaxf((v.y - mu) * sc + bb.y, 0.f);
    }
    {
        float mu = sm.z * inv, var = sq.z * inv - mu * mu;
        float sc = gg.z * rsqrtf(var + BN_EPS);
        o.z = fmaxf((v.z - mu) * sc + bb.z, 0.f);
    }
    {
        float mu = sm.w * inv, var = sq.w * inv - mu * mu;
        float sc = gg.w * rsqrtf(var + BN_EPS);
        o.w = fmaxf((v.w - mu) * sc + bb.w, 0.f);
    }
    *(float4*)(out + off) = o;
}

// ---------------------------------------------------------------------------
// Global mean pool: one block per graph; batch is sorted, so binary-search the
// segment bounds. No atomics.
// ---------------------------------------------------------------------------
__device__ __forceinline__ int lower_bound_batch(const int* __restrict__ b, int val) {
    int lo = 0, hi = NN;
    while (lo < hi) {
        int mid = (lo + hi) >> 1;
        if (b[mid] < val) lo = mid + 1;
        else hi = mid;
    }
    return lo;
}

__global__ __launch_bounds__(256)
void pool_kernel(const float* __restrict__ x, const int* __restrict__ batch,
                 float* __restrict__ out) {
    int gph = blockIdx.x;
    int s = lower_bound_batch(batch, gph);
    int e = lower_bound_batch(batch, gph + 1);
    int col = threadIdx.x & 63;
    int rl = threadIdx.x >> 6;
    float sum = 0.f;
    for (int r = s + rl; r < e; r += 4) sum += x[(size_t)r * HD + col];
    __shared__ float red[4][64];
    red[rl][col] = sum;
    __syncthreads();
    if (rl == 0) {
        sum = red[0][col] + red[1][col] + red[2][col] + red[3][col];
        float cnt = (float)(e - s);
        out[gph * HD + col] = sum / fmaxf(cnt, 1.f);
    }
}

extern "C" void kernel_launch(void* const* d_in, const int* in_sizes, int n_in,
                              void* d_out, int out_size, void* d_ws, size_t ws_size,
                              hipStream_t stream) {
    const float* x = (const float*)d_in[0];
    const int* ei = (const int*)d_in[1];
    const int* batch = (const int*)d_in[2];
    const float* W1_0 = (const float*)d_in[3];
    const float* b1_0 = (const float*)d_in[4];
    const float* W2_0 = (const float*)d_in[5];
    const float* b2_0 = (const float*)d_in[6];
    const float* g_0 = (const float*)d_in[7];
    const float* be_0 = (const float*)d_in[8];
    const float* W1_1 = (const float*)d_in[9];
    const float* b1_1 = (const float*)d_in[10];
    const float* W2_1 = (const float*)d_in[11];
    const float* b2_1 = (const float*)d_in[12];
    const float* g_1 = (const float*)d_in[13];
    const float* be_1 = (const float*)d_in[14];

    float* out = (float*)d_out;
    float* buf_h = (float*)d_ws;                 // agg, then h2 in-place (3.2M f32)
    float* buf_x1 = buf_h + (size_t)NN * HD;     // layer-0 output (3.2M f32)
    float* stats = buf_x1 + (size_t)NN * HD;     // 128 f32 (sum | sumsq)

    const size_t xbytes = (size_t)NN * HD * sizeof(float);
    dim3 b256(256);
    int scat_grid = (int)(((long)NE * 16 + 255) / 256);
    int mlp_grid = (NN + 255) / 256;
    int norm_grid = (NN * HD / 4 + 255) / 256;

    // ---- layer 0 ----
    hipMemsetAsync(buf_h, 0, xbytes, stream);
    scatter_kernel<<<scat_grid, b256, 0, stream>>>(x, ei, buf_h);
    mlp_kernel<<<mlp_grid, b256, 0, stream>>>(x, buf_h, W1_0, b1_0, W2_0, b2_0);
    hipMemsetAsync(stats, 0, 128 * sizeof(float), stream);
    stats_kernel<<<250, b256, 0, stream>>>(buf_h, stats);
    norm_kernel<<<norm_grid, b256, 0, stream>>>(buf_h, stats, g_0, be_0, buf_x1);

    // ---- layer 1 ----
    hipMemsetAsync(buf_h, 0, xbytes, stream);
    scatter_kernel<<<scat_grid, b256, 0, stream>>>(buf_x1, ei, buf_h);
    mlp_kernel<<<mlp_grid, b256, 0, stream>>>(buf_x1, buf_h, W1_1, b1_1, W2_1, b2_1);
    hipMemsetAsync(stats, 0, 128 * sizeof(float), stream);
    stats_kernel<<<250, b256, 0, stream>>>(buf_h, stats);
    norm_kernel<<<norm_grid, b256, 0, stream>>>(buf_h, stats, g_1, be_1, out);

    // ---- pool ----
    pool_kernel<<<NG, b256, 0, stream>>>(out, batch, out + (size_t)NN * HD);
}

// Round 2
// 486.590 us; speedup vs baseline: 3.7876x; 3.7876x over previous
//
#include <hip/hip_runtime.h>

// GIN: 2 x (CSR gather-sum + MLP(64->64->64) + BatchNorm + ReLU) + mean pool
// N=50000 nodes, E=800000 edges, H=64, G=16 graphs. All fp32.
// R2: replaced 51.2M-float-atomic scatter (800MB WRITE_SIZE, 681us/layer) with
// per-call CSR build + wave-per-row gather; parallelized pool (was 16 blocks).

constexpr int NN = 50000;
constexpr int NE = 800000;
constexpr int HD = 64;
constexpr int NG = 16;
constexpr float BN_EPS = 1e-5f;
constexpr int SCAN_BLOCKS = (NN + 255) / 256;  // 196

// ---------------------------------------------------------------------------
// CSR build: degree histogram -> exclusive scan -> edge placement.
// ---------------------------------------------------------------------------
__global__ __launch_bounds__(256)
void count_kernel(const int* __restrict__ ei, int* __restrict__ cnt) {
    int e = blockIdx.x * 256 + threadIdx.x;
    if (e >= NE) return;
    atomicAdd(&cnt[ei[NE + e]], 1);
}

// Per-block inclusive scan of 256-elem chunks; writes exclusive values + total.
__global__ __launch_bounds__(256)
void scan1_kernel(const int* __restrict__ cnt, int* __restrict__ row_ptr,
                  int* __restrict__ partials) {
    int i = blockIdx.x * 256 + threadIdx.x;
    int v = (i < NN) ? cnt[i] : 0;
    __shared__ int s[256];
    s[threadIdx.x] = v;
    __syncthreads();
#pragma unroll
    for (int off = 1; off < 256; off <<= 1) {
        int add = (threadIdx.x >= off) ? s[threadIdx.x - off] : 0;
        __syncthreads();
        s[threadIdx.x] += add;
        __syncthreads();
    }
    if (i < NN) row_ptr[i] = s[threadIdx.x] - v;  // exclusive
    if (threadIdx.x == 255) partials[blockIdx.x] = s[255];
}

__global__ __launch_bounds__(256)
void scan2_kernel(int* __restrict__ partials, int* __restrict__ poffs) {
    int v = (threadIdx.x < SCAN_BLOCKS) ? partials[threadIdx.x] : 0;
    __shared__ int s[256];
    s[threadIdx.x] = v;
    __syncthreads();
#pragma unroll
    for (int off = 1; off < 256; off <<= 1) {
        int add = (threadIdx.x >= off) ? s[threadIdx.x - off] : 0;
        __syncthreads();
        s[threadIdx.x] += add;
        __syncthreads();
    }
    poffs[threadIdx.x] = s[threadIdx.x] - v;  // exclusive
}

__global__ __launch_bounds__(256)
void scan3_kernel(int* __restrict__ row_ptr, const int* __restrict__ poffs,
                  int* __restrict__ cursor) {
    int i = blockIdx.x * 256 + threadIdx.x;
    if (i < NN) {
        int v = row_ptr[i] + poffs[blockIdx.x];
        row_ptr[i] = v;
        cursor[i] = v;
    }
    if (i == 0) row_ptr[NN] = NE;
}

__global__ __launch_bounds__(256)
void place_kernel(const int* __restrict__ ei, int* __restrict__ cursor,
                  int* __restrict__ csr) {
    int e = blockIdx.x * 256 + threadIdx.x;
    if (e >= NE) return;
    int pos = atomicAdd(&cursor[ei[NE + e]], 1);
    csr[pos] = ei[e];
}

// ---------------------------------------------------------------------------
// Aggregation: one wave per dst row. h[r] = x[r] + sum_{nb in csr[r]} x[nb].
// Neighbor ids preloaded lane-parallel, broadcast via shfl (no dependent
// scalar load per iteration); x-row gathers are 256B coalesced per wave.
// ---------------------------------------------------------------------------
__global__ __launch_bounds__(256)
void agg_kernel(const float* __restrict__ x, const int* __restrict__ row_ptr,
                const int* __restrict__ csr, float* __restrict__ h) {
    int row = blockIdx.x * 4 + (threadIdx.x >> 6);
    int lane = threadIdx.x & 63;
    int s = row_ptr[row], e = row_ptr[row + 1];
    int cnt = e - s;
    int ids = (lane < cnt) ? csr[s + lane] : 0;
    float acc = x[(size_t)row * HD + lane];
    int m = min(cnt, 64);
    for (int j = 0; j < m; j++) {
        int nb = __shfl(ids, j);
        acc += x[(size_t)nb * HD + lane];
    }
    for (int j = s + 64; j < e; j++) {  // degree > 64 fallback (rare/never)
        int nb = csr[j];
        acc += x[(size_t)nb * HD + lane];
    }
    h[(size_t)row * HD + lane] = acc;
}

// ---------------------------------------------------------------------------
// Fused MLP: h2 = ReLU(h @ W1 + b1) @ W2 + b2, in-place over h (h = x+agg
// already). Thread-per-row; W1/W2 in LDS; static register indices.
// ---------------------------------------------------------------------------
__global__ __launch_bounds__(256)
void mlp_kernel(float* __restrict__ h,
                const float* __restrict__ W1, const float* __restrict__ b1,
                const float* __restrict__ W2, const float* __restrict__ b2) {
    __shared__ float sW1[64 * 64];
    __shared__ float sW2[64 * 64];
    __shared__ float sb1[64];
    __shared__ float sb2[64];
    for (int i = threadIdx.x; i < 4096; i += 256) {
        sW1[i] = W1[i];
        sW2[i] = W2[i];
    }
    if (threadIdx.x < 64) {
        sb1[threadIdx.x] = b1[threadIdx.x];
        sb2[threadIdx.x] = b2[threadIdx.x];
    }
    __syncthreads();
    int row = blockIdx.x * 256 + threadIdx.x;
    if (row >= NN) return;

    float hv[64];
    {
        const float4* hr = (const float4*)(h + (size_t)row * HD);
#pragma unroll
        for (int i = 0; i < 16; i++) {
            float4 a = hr[i];
            hv[4 * i + 0] = a.x;
            hv[4 * i + 1] = a.y;
            hv[4 * i + 2] = a.z;
            hv[4 * i + 3] = a.w;
        }
    }

    float acc[64];
#pragma unroll
    for (int j = 0; j < 64; j++) acc[j] = sb2[j];

#pragma unroll 1
    for (int c = 0; c < 8; c++) {
        float t[8];
#pragma unroll
        for (int i = 0; i < 8; i++) t[i] = sb1[c * 8 + i];
        const float* w1c = sW1 + c * 8;
#pragma unroll
        for (int k = 0; k < 64; k++) {
            float a = hv[k];
#pragma unroll
            for (int i = 0; i < 8; i++) t[i] += a * w1c[k * 64 + i];
        }
#pragma unroll
        for (int i = 0; i < 8; i++) t[i] = fmaxf(t[i], 0.f);
        const float* w2c = sW2 + c * 8 * 64;
#pragma unroll
        for (int i = 0; i < 8; i++) {
            float a = t[i];
#pragma unroll
            for (int j = 0; j < 64; j++) acc[j] += a * w2c[i * 64 + j];
        }
    }

    float4* hr = (float4*)(h + (size_t)row * HD);
#pragma unroll
    for (int i = 0; i < 16; i++)
        hr[i] = make_float4(acc[4 * i], acc[4 * i + 1], acc[4 * i + 2], acc[4 * i + 3]);
}

// ---------------------------------------------------------------------------
// Column sum / sumsq over all N rows (BatchNorm batch stats).
// ---------------------------------------------------------------------------
__global__ __launch_bounds__(256)
void stats_kernel(const float* __restrict__ h, float* __restrict__ stats) {
    int col = threadIdx.x & 63;
    int rl = threadIdx.x >> 6;
    float s = 0.f, ss = 0.f;
    for (int r = blockIdx.x * 4 + rl; r < NN; r += gridDim.x * 4) {
        float v = h[(size_t)r * HD + col];
        s += v;
        ss += v * v;
    }
    __shared__ float red[2][4][64];
    red[0][rl][col] = s;
    red[1][rl][col] = ss;
    __syncthreads();
    if (rl == 0) {
        s = red[0][0][col] + red[0][1][col] + red[0][2][col] + red[0][3][col];
        ss = red[1][0][col] + red[1][1][col] + red[1][2][col] + red[1][3][col];
        atomicAdd(stats + col, s);
        atomicAdd(stats + 64 + col, ss);
    }
}

// ---------------------------------------------------------------------------
// BatchNorm (batch stats, biased var) + affine + ReLU.
// ---------------------------------------------------------------------------
__global__ __launch_bounds__(256)
void norm_kernel(const float* __restrict__ h, const float* __restrict__ stats,
                 const float* __restrict__ g, const float* __restrict__ be,
                 float* __restrict__ out) {
    size_t i4 = (size_t)blockIdx.x * 256 + threadIdx.x;
    if (i4 >= (size_t)NN * HD / 4) return;
    size_t off = i4 * 4;
    int col = (int)(off & 63);
    float4 v = *(const float4*)(h + off);
    float4 sm = *(const float4*)(stats + col);
    float4 sq = *(const float4*)(stats + 64 + col);
    float4 gg = *(const float4*)(g + col);
    float4 bb = *(const float4*)(be + col);
    const float inv = 1.f / (float)NN;
    float4 o;
    {
        float mu = sm.x * inv, var = sq.x * inv - mu * mu;
        float sc = gg.x * rsqrtf(var + BN_EPS);
        o.x = fmaxf((v.x - mu) * sc + bb.x, 0.f);
    }
    {
        float mu = sm.y * inv, var = sq.y * inv - mu * mu;
        float sc = gg.y * rsqrtf(var + BN_EPS);
        o.y = fmaxf((v.y - mu) * sc + bb.y, 0.f);
    }
    {
        float mu = sm.z * inv, var = sq.z * inv - mu * mu;
        float sc = gg.z * rsqrtf(var + BN_EPS);
        o.z = fmaxf((v.z - mu) * sc + bb.z, 0.f);
    }
    {
        float mu = sm.w * inv, var = sq.w * inv - mu * mu;
        float sc = gg.w * rsqrtf(var + BN_EPS);
        o.w = fmaxf((v.w - mu) * sc + bb.w, 0.f);
    }
    *(float4*)(out + off) = o;
}

// ---------------------------------------------------------------------------
// Mean pool, parallel: 200 blocks of partial sums (batch is sorted, so each
// thread flushes at graph transitions), then a tiny finalize.
// ---------------------------------------------------------------------------
__global__ __launch_bounds__(256)
void pool_partial_kernel(const float* __restrict__ x, const int* __restrict__ batch,
                         float* __restrict__ sums) {
    int col = threadIdx.x & 63;
    int rl = threadIdx.x >> 6;
    int rs = blockIdx.x * 250;
    int re = rs + 250;
    int cur = -1;
    float acc = 0.f;
    for (int r = rs + rl; r < re; r += 4) {
        int g = batch[r];
        float v = x[(size_t)r * HD + col];
        if (g != cur) {
            if (cur >= 0) atomicAdd(&sums[cur * HD + col], acc);
            cur = g;
            acc = v;
        } else {
            acc += v;
        }
    }
    if (cur >= 0) atomicAdd(&sums[cur * HD + col], acc);
}

__device__ __forceinline__ int lower_bound_batch(const int* __restrict__ b, int val) {
    int lo = 0, hi = NN;
    while (lo < hi) {
        int mid = (lo + hi) >> 1;
        if (b[mid] < val) lo = mid + 1;
        else hi = mid;
    }
    return lo;
}

__global__ __launch_bounds__(1024)
void pool_finalize_kernel(const float* __restrict__ sums, const int* __restrict__ batch,
                          float* __restrict__ out) {
    int g = threadIdx.x >> 6;
    int col = threadIdx.x & 63;
    int s = lower_bound_batch(batch, g);
    int e = lower_bound_batch(batch, g + 1);
    float cnt = (float)(e - s);
    out[g * HD + col] = sums[g * HD + col] / fmaxf(cnt, 1.f);
}

extern "C" void kernel_launch(void* const* d_in, const int* in_sizes, int n_in,
                              void* d_out, int out_size, void* d_ws, size_t ws_size,
                              hipStream_t stream) {
    const float* x = (const float*)d_in[0];
    const int* ei = (const int*)d_in[1];
    const int* batch = (const int*)d_in[2];
    const float* W1_0 = (const float*)d_in[3];
    const float* b1_0 = (const float*)d_in[4];
    const float* W2_0 = (const float*)d_in[5];
    const float* b2_0 = (const float*)d_in[6];
    const float* g_0 = (const float*)d_in[7];
    const float* be_0 = (const float*)d_in[8];
    const float* W1_1 = (const float*)d_in[9];
    const float* b1_1 = (const float*)d_in[10];
    const float* W2_1 = (const float*)d_in[11];
    const float* b2_1 = (const float*)d_in[12];
    const float* g_1 = (const float*)d_in[13];
    const float* be_1 = (const float*)d_in[14];

    float* out = (float*)d_out;
    float* x1 = out;  // layer-0 output staged in d_out, overwritten by layer 1

    // workspace layout
    float* buf_h = (float*)d_ws;                     // 3.2M f32
    float* stats = buf_h + (size_t)NN * HD;          // 128 f32
    float* psums = stats + 128;                      // 1024 f32
    int* row_ptr = (int*)(psums + 1024);             // NN+1
    int* cnt = row_ptr + (NN + 2);                   // NN (also cursor)
    int* partials = cnt + NN;                        // 256
    int* poffs = partials + 256;                     // 256
    int* csr = poffs + 256;                          // NE

    dim3 b256(256);
    int egrid = (NE + 255) / 256;        // 3125
    int mlp_grid = (NN + 255) / 256;     // 196
    int norm_grid = (NN * HD / 4 + 255) / 256;
    int agg_grid = NN / 4;               // 12500, one wave per row

    // ---- CSR build (shared by both layers) ----
    hipMemsetAsync(cnt, 0, NN * sizeof(int), stream);
    count_kernel<<<egrid, b256, 0, stream>>>(ei, cnt);
    scan1_kernel<<<SCAN_BLOCKS, b256, 0, stream>>>(cnt, row_ptr, partials);
    scan2_kernel<<<1, b256, 0, stream>>>(partials, poffs);
    scan3_kernel<<<SCAN_BLOCKS, b256, 0, stream>>>(row_ptr, poffs, cnt);
    place_kernel<<<egrid, b256, 0, stream>>>(ei, cnt, csr);

    // ---- layer 0 ----
    agg_kernel<<<agg_grid, b256, 0, stream>>>(x, row_ptr, csr, buf_h);
    mlp_kernel<<<mlp_grid, b256, 0, stream>>>(buf_h, W1_0, b1_0, W2_0, b2_0);
    hipMemsetAsync(stats, 0, 128 * sizeof(float), stream);
    stats_kernel<<<250, b256, 0, stream>>>(buf_h, stats);
    norm_kernel<<<norm_grid, b256, 0, stream>>>(buf_h, stats, g_0, be_0, x1);

    // ---- layer 1 ----
    agg_kernel<<<agg_grid, b256, 0, stream>>>(x1, row_ptr, csr, buf_h);
    mlp_kernel<<<mlp_grid, b256, 0, stream>>>(buf_h, W1_1, b1_1, W2_1, b2_1);
    hipMemsetAsync(stats, 0, 128 * sizeof(float), stream);
    stats_kernel<<<250, b256, 0, stream>>>(buf_h, stats);
    norm_kernel<<<norm_grid, b256, 0, stream>>>(buf_h, stats, g_1, be_1, out);

    // ---- pool ----
    hipMemsetAsync(psums, 0, 1024 * sizeof(float), stream);
    pool_partial_kernel<<<200, b256, 0, stream>>>(out, batch, psums);
    pool_finalize_kernel<<<1, dim3(1024), 0, stream>>>(psums, batch, out + (size_t)NN * HD);
}

// Round 4
// 448.038 us; speedup vs baseline: 4.1135x; 1.0860x over previous
//
#include <hip/hip_runtime.h>

// GIN: 2 x (CSR gather-sum + MLP(64->64->64) + BatchNorm + ReLU) + mean pool
// N=50000 nodes, E=800000 edges, H=64, G=16 graphs. All fp32.
// R4: reverted R3's scalar-load MLP (nondeterministic + 8x slow). MLP now:
// 64 rows/block, 4 waves x 16 cols, W staged in LDS and read as float4
// broadcasts (4 fma per ds_read_b128), W1/W2 sequentially in one buffer
// (49.9KB LDS -> 3 blocks/CU). MLP writes d_out (not in-place); norm is
// elementwise in-place.

constexpr int NN = 50000;
constexpr int NE = 800000;
constexpr int HD = 64;
constexpr int NG = 16;
constexpr float BN_EPS = 1e-5f;
constexpr int SCAN_BLOCKS = (NN + 255) / 256;  // 196

// ---------------------------------------------------------------------------
// CSR build: degree histogram -> exclusive scan -> edge placement.
// ---------------------------------------------------------------------------
__global__ __launch_bounds__(256)
void count_kernel(const int* __restrict__ ei, int* __restrict__ cnt) {
    int e = blockIdx.x * 256 + threadIdx.x;
    if (e >= NE) return;
    atomicAdd(&cnt[ei[NE + e]], 1);
}

__global__ __launch_bounds__(256)
void scan1_kernel(const int* __restrict__ cnt, int* __restrict__ row_ptr,
                  int* __restrict__ partials) {
    int i = blockIdx.x * 256 + threadIdx.x;
    int v = (i < NN) ? cnt[i] : 0;
    __shared__ int s[256];
    s[threadIdx.x] = v;
    __syncthreads();
#pragma unroll
    for (int off = 1; off < 256; off <<= 1) {
        int add = (threadIdx.x >= off) ? s[threadIdx.x - off] : 0;
        __syncthreads();
        s[threadIdx.x] += add;
        __syncthreads();
    }
    if (i < NN) row_ptr[i] = s[threadIdx.x] - v;  // exclusive
    if (threadIdx.x == 255) partials[blockIdx.x] = s[255];
}

__global__ __launch_bounds__(256)
void scan2_kernel(int* __restrict__ partials, int* __restrict__ poffs) {
    int v = (threadIdx.x < SCAN_BLOCKS) ? partials[threadIdx.x] : 0;
    __shared__ int s[256];
    s[threadIdx.x] = v;
    __syncthreads();
#pragma unroll
    for (int off = 1; off < 256; off <<= 1) {
        int add = (threadIdx.x >= off) ? s[threadIdx.x - off] : 0;
        __syncthreads();
        s[threadIdx.x] += add;
        __syncthreads();
    }
    poffs[threadIdx.x] = s[threadIdx.x] - v;  // exclusive
}

__global__ __launch_bounds__(256)
void scan3_kernel(int* __restrict__ row_ptr, const int* __restrict__ poffs,
                  int* __restrict__ cursor) {
    int i = blockIdx.x * 256 + threadIdx.x;
    if (i < NN) {
        int v = row_ptr[i] + poffs[blockIdx.x];
        row_ptr[i] = v;
        cursor[i] = v;
    }
    if (i == 0) row_ptr[NN] = NE;
}

__global__ __launch_bounds__(256)
void place_kernel(const int* __restrict__ ei, int* __restrict__ cursor,
                  int* __restrict__ csr) {
    int e = blockIdx.x * 256 + threadIdx.x;
    if (e >= NE) return;
    int pos = atomicAdd(&cursor[ei[NE + e]], 1);
    csr[pos] = ei[e];
}

// ---------------------------------------------------------------------------
// Aggregation: one wave per dst row. h[r] = x[r] + sum_{nb in csr[r]} x[nb].
// ---------------------------------------------------------------------------
__global__ __launch_bounds__(256)
void agg_kernel(const float* __restrict__ x, const int* __restrict__ row_ptr,
                const int* __restrict__ csr, float* __restrict__ h) {
    int row = blockIdx.x * 4 + (threadIdx.x >> 6);
    int lane = threadIdx.x & 63;
    int s = row_ptr[row], e = row_ptr[row + 1];
    int cnt = e - s;
    int ids = (lane < cnt) ? csr[s + lane] : 0;
    float acc = x[(size_t)row * HD + lane];
    int m = min(cnt, 64);
    for (int j = 0; j < m; j++) {
        int nb = __shfl(ids, j);
        acc += x[(size_t)nb * HD + lane];
    }
    for (int j = s + 64; j < e; j++) {  // degree > 64 fallback
        int nb = csr[j];
        acc += x[(size_t)nb * HD + lane];
    }
    h[(size_t)row * HD + lane] = acc;
}

// ---------------------------------------------------------------------------
// Fused MLP: hout = ReLU(hin @ W1 + b1) @ W2 + b2 (bias+ReLU in regs).
// Block = 64 rows x 256 threads; wave wv owns cols [wv*16,+16), lane = row.
// Rows/t-matrix in LDS stride 65 ((lane+k)%32 banks: 2-way, free). W staged
// in one LDS buffer (W1 then W2) and read as wave-uniform float4 broadcasts
// (same-address -> conflict-free, 4 fma per ds_read_b128).
// ---------------------------------------------------------------------------
__global__ __launch_bounds__(256)
void mlp_kernel(const float* __restrict__ hin, float* __restrict__ hout,
                const float* __restrict__ W1, const float* __restrict__ b1,
                const float* __restrict__ W2, const float* __restrict__ b2) {
    __shared__ float sh[64 * 65];
    __shared__ float st[64 * 65];
    __shared__ float sW[64 * 64];
    __shared__ float sb[64];
    int tid = threadIdx.x;
    int base = blockIdx.x * 64;

    for (int i = tid; i < 4096; i += 256) sW[i] = W1[i];
    if (tid < 64) sb[tid] = b1[tid];
#pragma unroll
    for (int i = 0; i < 16; i++) {
        int idx = tid + 256 * i;  // 0..4095
        int row = idx >> 6, col = idx & 63;
        int grow = base + row;
        sh[row * 65 + col] = (grow < NN) ? hin[(size_t)grow * HD + col] : 0.f;
    }
    __syncthreads();

    int wv = tid >> 6;
    int lane = tid & 63;

    float acc[16];
    // ---- GEMM1 + ReLU ----
#pragma unroll
    for (int j = 0; j < 16; j++) acc[j] = sb[wv * 16 + j];
    for (int k = 0; k < 64; k++) {
        float a = sh[lane * 65 + k];
        const float4* wr = (const float4*)(sW + k * 64 + wv * 16);
#pragma unroll
        for (int q = 0; q < 4; q++) {
            float4 w = wr[q];
            acc[4 * q + 0] = fmaf(a, w.x, acc[4 * q + 0]);
            acc[4 * q + 1] = fmaf(a, w.y, acc[4 * q + 1]);
            acc[4 * q + 2] = fmaf(a, w.z, acc[4 * q + 2]);
            acc[4 * q + 3] = fmaf(a, w.w, acc[4 * q + 3]);
        }
    }
#pragma unroll
    for (int j = 0; j < 16; j++) st[lane * 65 + wv * 16 + j] = fmaxf(acc[j], 0.f);
    __syncthreads();  // t ready; all W1 reads of sW complete

    // restage W2/b2 over the same buffers
    for (int i = tid; i < 4096; i += 256) sW[i] = W2[i];
    if (tid < 64) sb[tid] = b2[tid];
    __syncthreads();

    // ---- GEMM2 ----
#pragma unroll
    for (int j = 0; j < 16; j++) acc[j] = sb[wv * 16 + j];
    for (int k = 0; k < 64; k++) {
        float a = st[lane * 65 + k];
        const float4* wr = (const float4*)(sW + k * 64 + wv * 16);
#pragma unroll
        for (int q = 0; q < 4; q++) {
            float4 w = wr[q];
            acc[4 * q + 0] = fmaf(a, w.x, acc[4 * q + 0]);
            acc[4 * q + 1] = fmaf(a, w.y, acc[4 * q + 1]);
            acc[4 * q + 2] = fmaf(a, w.z, acc[4 * q + 2]);
            acc[4 * q + 3] = fmaf(a, w.w, acc[4 * q + 3]);
        }
    }
    __syncthreads();  // all st reads complete before overwrite
#pragma unroll
    for (int j = 0; j < 16; j++) st[lane * 65 + wv * 16 + j] = acc[j];
    __syncthreads();

    // coalesced store
#pragma unroll
    for (int i = 0; i < 16; i++) {
        int idx = tid + 256 * i;
        int row = idx >> 6, col = idx & 63;
        int grow = base + row;
        if (grow < NN) hout[(size_t)grow * HD + col] = st[row * 65 + col];
    }
}

// ---------------------------------------------------------------------------
// Column sum / sumsq over all N rows (BatchNorm batch stats).
// ---------------------------------------------------------------------------
__global__ __launch_bounds__(256)
void stats_kernel(const float* __restrict__ h, float* __restrict__ stats) {
    int col = threadIdx.x & 63;
    int rl = threadIdx.x >> 6;
    float s = 0.f, ss = 0.f;
    for (int r = blockIdx.x * 4 + rl; r < NN; r += gridDim.x * 4) {
        float v = h[(size_t)r * HD + col];
        s += v;
        ss += v * v;
    }
    __shared__ float red[2][4][64];
    red[0][rl][col] = s;
    red[1][rl][col] = ss;
    __syncthreads();
    if (rl == 0) {
        s = red[0][0][col] + red[0][1][col] + red[0][2][col] + red[0][3][col];
        ss = red[1][0][col] + red[1][1][col] + red[1][2][col] + red[1][3][col];
        atomicAdd(stats + col, s);
        atomicAdd(stats + 64 + col, ss);
    }
}

// ---------------------------------------------------------------------------
// BatchNorm (batch stats, biased var) + affine + ReLU. Elementwise, in-place.
// ---------------------------------------------------------------------------
__global__ __launch_bounds__(256)
void norm_kernel(float* h, const float* __restrict__ stats,
                 const float* __restrict__ g, const float* __restrict__ be) {
    size_t i4 = (size_t)blockIdx.x * 256 + threadIdx.x;
    if (i4 >= (size_t)NN * HD / 4) return;
    size_t off = i4 * 4;
    int col = (int)(off & 63);
    float4 v = *(const float4*)(h + off);
    float4 sm = *(const float4*)(stats + col);
    float4 sq = *(const float4*)(stats + 64 + col);
    float4 gg = *(const float4*)(g + col);
    float4 bb = *(const float4*)(be + col);
    const float inv = 1.f / (float)NN;
    float4 o;
    {
        float mu = sm.x * inv, var = sq.x * inv - mu * mu;
        float sc = gg.x * rsqrtf(var + BN_EPS);
        o.x = fmaxf((v.x - mu) * sc + bb.x, 0.f);
    }
    {
        float mu = sm.y * inv, var = sq.y * inv - mu * mu;
        float sc = gg.y * rsqrtf(var + BN_EPS);
        o.y = fmaxf((v.y - mu) * sc + bb.y, 0.f);
    }
    {
        float mu = sm.z * inv, var = sq.z * inv - mu * mu;
        float sc = gg.z * rsqrtf(var + BN_EPS);
        o.z = fmaxf((v.z - mu) * sc + bb.z, 0.f);
    }
    {
        float mu = sm.w * inv, var = sq.w * inv - mu * mu;
        float sc = gg.w * rsqrtf(var + BN_EPS);
        o.w = fmaxf((v.w - mu) * sc + bb.w, 0.f);
    }
    *(float4*)(h + off) = o;
}

// ---------------------------------------------------------------------------
// Mean pool: 200 partial blocks + tiny finalize.
// ---------------------------------------------------------------------------
__global__ __launch_bounds__(256)
void pool_partial_kernel(const float* __restrict__ x, const int* __restrict__ batch,
                         float* __restrict__ sums) {
    int col = threadIdx.x & 63;
    int rl = threadIdx.x >> 6;
    int rs = blockIdx.x * 250;
    int re = rs + 250;
    int cur = -1;
    float acc = 0.f;
    for (int r = rs + rl; r < re; r += 4) {
        int g = batch[r];
        float v = x[(size_t)r * HD + col];
        if (g != cur) {
            if (cur >= 0) atomicAdd(&sums[cur * HD + col], acc);
            cur = g;
            acc = v;
        } else {
            acc += v;
        }
    }
    if (cur >= 0) atomicAdd(&sums[cur * HD + col], acc);
}

__device__ __forceinline__ int lower_bound_batch(const int* __restrict__ b, int val) {
    int lo = 0, hi = NN;
    while (lo < hi) {
        int mid = (lo + hi) >> 1;
        if (b[mid] < val) lo = mid + 1;
        else hi = mid;
    }
    return lo;
}

__global__ __launch_bounds__(1024)
void pool_finalize_kernel(const float* __restrict__ sums, const int* __restrict__ batch,
                          float* __restrict__ out) {
    int g = threadIdx.x >> 6;
    int col = threadIdx.x & 63;
    int s = lower_bound_batch(batch, g);
    int e = lower_bound_batch(batch, g + 1);
    float cnt = (float)(e - s);
    out[g * HD + col] = sums[g * HD + col] / fmaxf(cnt, 1.f);
}

extern "C" void kernel_launch(void* const* d_in, const int* in_sizes, int n_in,
                              void* d_out, int out_size, void* d_ws, size_t ws_size,
                              hipStream_t stream) {
    const float* x = (const float*)d_in[0];
    const int* ei = (const int*)d_in[1];
    const int* batch = (const int*)d_in[2];
    const float* W1_0 = (const float*)d_in[3];
    const float* b1_0 = (const float*)d_in[4];
    const float* W2_0 = (const float*)d_in[5];
    const float* b2_0 = (const float*)d_in[6];
    const float* g_0 = (const float*)d_in[7];
    const float* be_0 = (const float*)d_in[8];
    const float* W1_1 = (const float*)d_in[9];
    const float* b1_1 = (const float*)d_in[10];
    const float* W2_1 = (const float*)d_in[11];
    const float* b2_1 = (const float*)d_in[12];
    const float* g_1 = (const float*)d_in[13];
    const float* be_1 = (const float*)d_in[14];

    float* out = (float*)d_out;  // node output; also x1 staging between layers

    // workspace layout (max 16.4 MB, within proven budget)
    float* buf_h = (float*)d_ws;                     // 3.2M f32 (agg output)
    float* stats = buf_h + (size_t)NN * HD;          // 128 f32
    float* psums = stats + 128;                      // 1024 f32
    int* row_ptr = (int*)(psums + 1024);             // NN+1
    int* cnt = row_ptr + (NN + 2);                   // NN (also cursor)
    int* partials = cnt + NN;                        // 256
    int* poffs = partials + 256;                     // 256
    int* csr = poffs + 256;                          // NE

    dim3 b256(256);
    int egrid = (NE + 255) / 256;          // 3125
    int mlp_grid = (NN + 63) / 64;         // 782
    int norm_grid = (NN * HD / 4 + 255) / 256;
    int agg_grid = NN / 4;                 // 12500

    // ---- CSR build (shared by both layers) ----
    hipMemsetAsync(cnt, 0, NN * sizeof(int), stream);
    count_kernel<<<egrid, b256, 0, stream>>>(ei, cnt);
    scan1_kernel<<<SCAN_BLOCKS, b256, 0, stream>>>(cnt, row_ptr, partials);
    scan2_kernel<<<1, b256, 0, stream>>>(partials, poffs);
    scan3_kernel<<<SCAN_BLOCKS, b256, 0, stream>>>(row_ptr, poffs, cnt);
    place_kernel<<<egrid, b256, 0, stream>>>(ei, cnt, csr);

    // ---- layer 0 ----
    agg_kernel<<<agg_grid, b256, 0, stream>>>(x, row_ptr, csr, buf_h);
    mlp_kernel<<<mlp_grid, b256, 0, stream>>>(buf_h, out, W1_0, b1_0, W2_0, b2_0);
    hipMemsetAsync(stats, 0, 128 * sizeof(float), stream);
    stats_kernel<<<250, b256, 0, stream>>>(out, stats);
    norm_kernel<<<norm_grid, b256, 0, stream>>>(out, stats, g_0, be_0);

    // ---- layer 1 ----
    agg_kernel<<<agg_grid, b256, 0, stream>>>(out, row_ptr, csr, buf_h);
    mlp_kernel<<<mlp_grid, b256, 0, stream>>>(buf_h, out, W1_1, b1_1, W2_1, b2_1);
    hipMemsetAsync(stats, 0, 128 * sizeof(float), stream);
    stats_kernel<<<250, b256, 0, stream>>>(out, stats);
    norm_kernel<<<norm_grid, b256, 0, stream>>>(out, stats, g_1, be_1);

    // ---- pool ----
    hipMemsetAsync(psums, 0, 1024 * sizeof(float), stream);
    pool_partial_kernel<<<200, b256, 0, stream>>>(out, batch, psums);
    pool_finalize_kernel<<<1, dim3(1024), 0, stream>>>(psums, batch, out + (size_t)NN * HD);
}

// Round 5
// 437.900 us; speedup vs baseline: 4.2088x; 1.0232x over previous
//
#include <hip/hip_runtime.h>
#include <hip/hip_bf16.h>

// GIN: 2 x (CSR gather-sum + MLP(64->64->64) + BatchNorm + ReLU) + mean pool
// N=50000 nodes, E=800000 edges, H=64, G=16 graphs. fp32 in/out.
// R5: agg gathers neighbors from a bf16 feature copy (6.4MB table vs 12.8MB;
// R4 showed 80MB FETCH = 6.3x over-fetch from per-XCD L2 re-fetch of the fp32
// table). BN stats fused into MLP epilogue (stats_kernel deleted).

constexpr int NN = 50000;
constexpr int NE = 800000;
constexpr int HD = 64;
constexpr int NG = 16;
constexpr float BN_EPS = 1e-5f;
constexpr int SCAN_BLOCKS = (NN + 255) / 256;  // 196

// ---------------------------------------------------------------------------
// CSR build: degree histogram -> exclusive scan -> edge placement.
// ---------------------------------------------------------------------------
__global__ __launch_bounds__(256)
void count_kernel(const int* __restrict__ ei, int* __restrict__ cnt) {
    int e = blockIdx.x * 256 + threadIdx.x;
    if (e >= NE) return;
    atomicAdd(&cnt[ei[NE + e]], 1);
}

__global__ __launch_bounds__(256)
void scan1_kernel(const int* __restrict__ cnt, int* __restrict__ row_ptr,
                  int* __restrict__ partials) {
    int i = blockIdx.x * 256 + threadIdx.x;
    int v = (i < NN) ? cnt[i] : 0;
    __shared__ int s[256];
    s[threadIdx.x] = v;
    __syncthreads();
#pragma unroll
    for (int off = 1; off < 256; off <<= 1) {
        int add = (threadIdx.x >= off) ? s[threadIdx.x - off] : 0;
        __syncthreads();
        s[threadIdx.x] += add;
        __syncthreads();
    }
    if (i < NN) row_ptr[i] = s[threadIdx.x] - v;  // exclusive
    if (threadIdx.x == 255) partials[blockIdx.x] = s[255];
}

__global__ __launch_bounds__(256)
void scan2_kernel(int* __restrict__ partials, int* __restrict__ poffs) {
    int v = (threadIdx.x < SCAN_BLOCKS) ? partials[threadIdx.x] : 0;
    __shared__ int s[256];
    s[threadIdx.x] = v;
    __syncthreads();
#pragma unroll
    for (int off = 1; off < 256; off <<= 1) {
        int add = (threadIdx.x >= off) ? s[threadIdx.x - off] : 0;
        __syncthreads();
        s[threadIdx.x] += add;
        __syncthreads();
    }
    poffs[threadIdx.x] = s[threadIdx.x] - v;  // exclusive
}

__global__ __launch_bounds__(256)
void scan3_kernel(int* __restrict__ row_ptr, const int* __restrict__ poffs,
                  int* __restrict__ cursor) {
    int i = blockIdx.x * 256 + threadIdx.x;
    if (i < NN) {
        int v = row_ptr[i] + poffs[blockIdx.x];
        row_ptr[i] = v;
        cursor[i] = v;
    }
    if (i == 0) row_ptr[NN] = NE;
}

__global__ __launch_bounds__(256)
void place_kernel(const int* __restrict__ ei, int* __restrict__ cursor,
                  int* __restrict__ csr) {
    int e = blockIdx.x * 256 + threadIdx.x;
    if (e >= NE) return;
    int pos = atomicAdd(&cursor[ei[NE + e]], 1);
    csr[pos] = ei[e];
}

// ---------------------------------------------------------------------------
// fp32 -> bf16 table conversion (vectorized: float4 -> 4x bf16 packed 8B).
// ---------------------------------------------------------------------------
__global__ __launch_bounds__(256)
void x2bf_kernel(const float* __restrict__ x, __hip_bfloat16* __restrict__ xb) {
    int i4 = blockIdx.x * 256 + threadIdx.x;
    if (i4 >= NN * HD / 4) return;
    float4 v = *(const float4*)(x + (size_t)i4 * 4);
    union { ushort4 u; __hip_bfloat16 b[4]; } p;
    p.b[0] = __float2bfloat16(v.x);
    p.b[1] = __float2bfloat16(v.y);
    p.b[2] = __float2bfloat16(v.z);
    p.b[3] = __float2bfloat16(v.w);
    *(ushort4*)((unsigned short*)xb + (size_t)i4 * 4) = p.u;
}

// ---------------------------------------------------------------------------
// Aggregation: one wave per dst row. h[r] = x_f32[r] + sum_nb bf16(x)[nb].
// Neighbor gathers hit the 6.4MB bf16 table (vs 12.8MB fp32: halves HBM
// fetch and nearly fits per-XCD L2). Accumulation fp32.
// ---------------------------------------------------------------------------
__global__ __launch_bounds__(256)
void agg_kernel(const float* __restrict__ x, const __hip_bfloat16* __restrict__ xb,
                const int* __restrict__ row_ptr, const int* __restrict__ csr,
                float* __restrict__ h) {
    int row = blockIdx.x * 4 + (threadIdx.x >> 6);
    int lane = threadIdx.x & 63;
    int s = row_ptr[row], e = row_ptr[row + 1];
    int cnt = e - s;
    int ids = (lane < cnt) ? csr[s + lane] : 0;
    float acc = x[(size_t)row * HD + lane];
    int m = min(cnt, 64);
    for (int j = 0; j < m; j++) {
        int nb = __shfl(ids, j);
        acc += __bfloat162float(xb[(size_t)nb * HD + lane]);
    }
    for (int j = s + 64; j < e; j++) {  // degree > 64 fallback
        acc += __bfloat162float(xb[(size_t)csr[j] * HD + lane]);
    }
    h[(size_t)row * HD + lane] = acc;
}

// ---------------------------------------------------------------------------
// Fused MLP + BN-stats epilogue.
// hout = ReLU(hin @ W1 + b1) @ W2 + b2; per-block column sum/sumsq of hout
// (valid rows only) atomically added to stats[0:64]/stats[64:128].
// Block = 64 rows x 256 threads; wave wv owns cols [wv*16,+16), lane = row.
// W staged in LDS, wave-uniform float4 broadcasts (conflict-free).
// ---------------------------------------------------------------------------
__global__ __launch_bounds__(256)
void mlp_kernel(const float* __restrict__ hin, float* __restrict__ hout,
                const float* __restrict__ W1, const float* __restrict__ b1,
                const float* __restrict__ W2, const float* __restrict__ b2,
                float* __restrict__ stats) {
    __shared__ float sh[64 * 65];
    __shared__ float st[64 * 65];
    __shared__ float sW[64 * 64];
    __shared__ float sb[64];
    int tid = threadIdx.x;
    int base = blockIdx.x * 64;

    for (int i = tid; i < 4096; i += 256) sW[i] = W1[i];
    if (tid < 64) sb[tid] = b1[tid];
#pragma unroll
    for (int i = 0; i < 16; i++) {
        int idx = tid + 256 * i;  // 0..4095
        int row = idx >> 6, col = idx & 63;
        int grow = base + row;
        sh[row * 65 + col] = (grow < NN) ? hin[(size_t)grow * HD + col] : 0.f;
    }
    __syncthreads();

    int wv = tid >> 6;
    int lane = tid & 63;

    float acc[16];
    // ---- GEMM1 + ReLU ----
#pragma unroll
    for (int j = 0; j < 16; j++) acc[j] = sb[wv * 16 + j];
    for (int k = 0; k < 64; k++) {
        float a = sh[lane * 65 + k];
        const float4* wr = (const float4*)(sW + k * 64 + wv * 16);
#pragma unroll
        for (int q = 0; q < 4; q++) {
            float4 w = wr[q];
            acc[4 * q + 0] = fmaf(a, w.x, acc[4 * q + 0]);
            acc[4 * q + 1] = fmaf(a, w.y, acc[4 * q + 1]);
            acc[4 * q + 2] = fmaf(a, w.z, acc[4 * q + 2]);
            acc[4 * q + 3] = fmaf(a, w.w, acc[4 * q + 3]);
        }
    }
#pragma unroll
    for (int j = 0; j < 16; j++) st[lane * 65 + wv * 16 + j] = fmaxf(acc[j], 0.f);
    __syncthreads();  // t ready; all sh/sW reads complete

    // restage W2/b2
    for (int i = tid; i < 4096; i += 256) sW[i] = W2[i];
    if (tid < 64) sb[tid] = b2[tid];
    __syncthreads();

    // ---- GEMM2 ----
#pragma unroll
    for (int j = 0; j < 16; j++) acc[j] = sb[wv * 16 + j];
    for (int k = 0; k < 64; k++) {
        float a = st[lane * 65 + k];
        const float4* wr = (const float4*)(sW + k * 64 + wv * 16);
#pragma unroll
        for (int q = 0; q < 4; q++) {
            float4 w = wr[q];
            acc[4 * q + 0] = fmaf(a, w.x, acc[4 * q + 0]);
            acc[4 * q + 1] = fmaf(a, w.y, acc[4 * q + 1]);
            acc[4 * q + 2] = fmaf(a, w.z, acc[4 * q + 2]);
            acc[4 * q + 3] = fmaf(a, w.w, acc[4 * q + 3]);
        }
    }
    __syncthreads();  // all st reads complete before overwrite
#pragma unroll
    for (int j = 0; j < 16; j++) st[lane * 65 + wv * 16 + j] = acc[j];
    __syncthreads();

    // coalesced store
#pragma unroll
    for (int i = 0; i < 16; i++) {
        int idx = tid + 256 * i;
        int row = idx >> 6, col = idx & 63;
        int grow = base + row;
        if (grow < NN) hout[(size_t)grow * HD + col] = st[row * 65 + col];
    }

    // ---- fused BN-stats partials (sh is dead; reuse as reduction buffer) ----
    {
        int col = tid & 63;
        int r0 = (tid >> 6) * 16;
        float s = 0.f, ss = 0.f;
#pragma unroll
        for (int r = 0; r < 16; r++) {
            float v = (base + r0 + r < NN) ? st[(r0 + r) * 65 + col] : 0.f;
            s += v;
            ss += v * v;
        }
        sh[(tid >> 6) * 64 + col] = s;
        sh[256 + (tid >> 6) * 64 + col] = ss;
        __syncthreads();
        if (tid < 64) {
            float S = sh[col] + sh[64 + col] + sh[128 + col] + sh[192 + col];
            atomicAdd(stats + col, S);
        } else if (tid < 128) {
            float SS = sh[256 + col] + sh[320 + col] + sh[384 + col] + sh[448 + col];
            atomicAdd(stats + 64 + col, SS);
        }
    }
}

// ---------------------------------------------------------------------------
// BatchNorm (batch stats, biased var) + affine + ReLU. In-place fp32 +
// dual-write bf16 copy (gather table for the next layer's agg).
// ---------------------------------------------------------------------------
__global__ __launch_bounds__(256)
void norm_kernel(float* h, const float* __restrict__ stats,
                 const float* __restrict__ g, const float* __restrict__ be,
                 __hip_bfloat16* __restrict__ xb) {
    size_t i4 = (size_t)blockIdx.x * 256 + threadIdx.x;
    if (i4 >= (size_t)NN * HD / 4) return;
    size_t off = i4 * 4;
    int col = (int)(off & 63);
    float4 v = *(const float4*)(h + off);
    float4 sm = *(const float4*)(stats + col);
    float4 sq = *(const float4*)(stats + 64 + col);
    float4 gg = *(const float4*)(g + col);
    float4 bb = *(const float4*)(be + col);
    const float inv = 1.f / (float)NN;
    float4 o;
    {
        float mu = sm.x * inv, var = sq.x * inv - mu * mu;
        float sc = gg.x * rsqrtf(var + BN_EPS);
        o.x = fmaxf((v.x - mu) * sc + bb.x, 0.f);
    }
    {
        float mu = sm.y * inv, var = sq.y * inv - mu * mu;
        float sc = gg.y * rsqrtf(var + BN_EPS);
        o.y = fmaxf((v.y - mu) * sc + bb.y, 0.f);
    }
    {
        float mu = sm.z * inv, var = sq.z * inv - mu * mu;
        float sc = gg.z * rsqrtf(var + BN_EPS);
        o.z = fmaxf((v.z - mu) * sc + bb.z, 0.f);
    }
    {
        float mu = sm.w * inv, var = sq.w * inv - mu * mu;
        float sc = gg.w * rsqrtf(var + BN_EPS);
        o.w = fmaxf((v.w - mu) * sc + bb.w, 0.f);
    }
    *(float4*)(h + off) = o;
    union { ushort4 u; __hip_bfloat16 b[4]; } p;
    p.b[0] = __float2bfloat16(o.x);
    p.b[1] = __float2bfloat16(o.y);
    p.b[2] = __float2bfloat16(o.z);
    p.b[3] = __float2bfloat16(o.w);
    *(ushort4*)((unsigned short*)xb + off) = p.u;
}

// ---------------------------------------------------------------------------
// Mean pool: 200 partial blocks + tiny finalize.
// ---------------------------------------------------------------------------
__global__ __launch_bounds__(256)
void pool_partial_kernel(const float* __restrict__ x, const int* __restrict__ batch,
                         float* __restrict__ sums) {
    int col = threadIdx.x & 63;
    int rl = threadIdx.x >> 6;
    int rs = blockIdx.x * 250;
    int re = rs + 250;
    int cur = -1;
    float acc = 0.f;
    for (int r = rs + rl; r < re; r += 4) {
        int g = batch[r];
        float v = x[(size_t)r * HD + col];
        if (g != cur) {
            if (cur >= 0) atomicAdd(&sums[cur * HD + col], acc);
            cur = g;
            acc = v;
        } else {
            acc += v;
        }
    }
    if (cur >= 0) atomicAdd(&sums[cur * HD + col], acc);
}

__device__ __forceinline__ int lower_bound_batch(const int* __restrict__ b, int val) {
    int lo = 0, hi = NN;
    while (lo < hi) {
        int mid = (lo + hi) >> 1;
        if (b[mid] < val) lo = mid + 1;
        else hi = mid;
    }
    return lo;
}

__global__ __launch_bounds__(1024)
void pool_finalize_kernel(const float* __restrict__ sums, const int* __restrict__ batch,
                          float* __restrict__ out) {
    int g = threadIdx.x >> 6;
    int col = threadIdx.x & 63;
    int s = lower_bound_batch(batch, g);
    int e = lower_bound_batch(batch, g + 1);
    float cnt = (float)(e - s);
    out[g * HD + col] = sums[g * HD + col] / fmaxf(cnt, 1.f);
}

extern "C" void kernel_launch(void* const* d_in, const int* in_sizes, int n_in,
                              void* d_out, int out_size, void* d_ws, size_t ws_size,
                              hipStream_t stream) {
    const float* x = (const float*)d_in[0];
    const int* ei = (const int*)d_in[1];
    const int* batch = (const int*)d_in[2];
    const float* W1_0 = (const float*)d_in[3];
    const float* b1_0 = (const float*)d_in[4];
    const float* W2_0 = (const float*)d_in[5];
    const float* b2_0 = (const float*)d_in[6];
    const float* g_0 = (const float*)d_in[7];
    const float* be_0 = (const float*)d_in[8];
    const float* W1_1 = (const float*)d_in[9];
    const float* b1_1 = (const float*)d_in[10];
    const float* W2_1 = (const float*)d_in[11];
    const float* b2_1 = (const float*)d_in[12];
    const float* g_1 = (const float*)d_in[13];
    const float* be_1 = (const float*)d_in[14];

    float* out = (float*)d_out;  // node output; also x1 staging between layers

    // workspace layout (~23 MB, within proven 26 MB budget)
    float* buf_h = (float*)d_ws;                       // 3.2M f32 (agg output)
    float* stats = buf_h + (size_t)NN * HD;            // 128 f32
    float* psums = stats + 128;                        // 1024 f32
    int* row_ptr = (int*)(psums + 1024);               // NN+1
    int* cnt = row_ptr + (NN + 2);                     // NN (also cursor)
    int* partials = cnt + NN;                          // 256
    int* poffs = partials + 256;                       // 256
    int* csr = poffs + 256;                            // NE
    __hip_bfloat16* xb = (__hip_bfloat16*)(csr + NE);  // 3.2M bf16 gather table

    dim3 b256(256);
    int egrid = (NE + 255) / 256;          // 3125
    int mlp_grid = (NN + 63) / 64;         // 782
    int norm_grid = (NN * HD / 4 + 255) / 256;
    int agg_grid = NN / 4;                 // 12500

    // ---- CSR build (shared by both layers) ----
    hipMemsetAsync(cnt, 0, NN * sizeof(int), stream);
    count_kernel<<<egrid, b256, 0, stream>>>(ei, cnt);
    scan1_kernel<<<SCAN_BLOCKS, b256, 0, stream>>>(cnt, row_ptr, partials);
    scan2_kernel<<<1, b256, 0, stream>>>(partials, poffs);
    scan3_kernel<<<SCAN_BLOCKS, b256, 0, stream>>>(row_ptr, poffs, cnt);
    place_kernel<<<egrid, b256, 0, stream>>>(ei, cnt, csr);

    // ---- layer 0 ----
    x2bf_kernel<<<norm_grid, b256, 0, stream>>>(x, xb);
    agg_kernel<<<agg_grid, b256, 0, stream>>>(x, xb, row_ptr, csr, buf_h);
    hipMemsetAsync(stats, 0, 128 * sizeof(float), stream);
    mlp_kernel<<<mlp_grid, b256, 0, stream>>>(buf_h, out, W1_0, b1_0, W2_0, b2_0, stats);
    norm_kernel<<<norm_grid, b256, 0, stream>>>(out, stats, g_0, be_0, xb);

    // ---- layer 1 ----
    agg_kernel<<<agg_grid, b256, 0, stream>>>(out, xb, row_ptr, csr, buf_h);
    hipMemsetAsync(stats, 0, 128 * sizeof(float), stream);
    mlp_kernel<<<mlp_grid, b256, 0, stream>>>(buf_h, out, W1_1, b1_1, W2_1, b2_1, stats);
    norm_kernel<<<norm_grid, b256, 0, stream>>>(out, stats, g_1, be_1, xb);

    // ---- pool ----
    hipMemsetAsync(psums, 0, 1024 * sizeof(float), stream);
    pool_partial_kernel<<<200, b256, 0, stream>>>(out, batch, psums);
    pool_finalize_kernel<<<1, dim3(1024), 0, stream>>>(psums, batch, out + (size_t)NN * HD);
}

// Round 6
// 382.315 us; speedup vs baseline: 4.8207x; 1.1454x over previous
//
#include <hip/hip_runtime.h>
#include <hip/hip_bf16.h>

// GIN: 2 x (CSR gather-sum + MLP(64->64->64) + BatchNorm + ReLU) + mean pool
// N=50000 nodes, E=800000 edges, H=64, G=16 graphs. fp32 in/out.
// R6: MLP now 2 rows/thread (128 rows/block): per-k LDS cost (2 b32 + 4 b128
// = 60 cyc) now amortized over 32 FMAs (64 VALU cyc) -> VALU-bound, was
// LDS-pipe-bound at 16 FMAs (R5: 56us, VALUBusy 12%). Input/t/output share one
// LDS tile (dead after each phase; barriered) to stay at ~52KB -> 3 blocks/CU.

constexpr int NN = 50000;
constexpr int NE = 800000;
constexpr int HD = 64;
constexpr int NG = 16;
constexpr float BN_EPS = 1e-5f;
constexpr int SCAN_BLOCKS = (NN + 255) / 256;  // 196

// ---------------------------------------------------------------------------
// CSR build: degree histogram -> exclusive scan -> edge placement.
// ---------------------------------------------------------------------------
__global__ __launch_bounds__(256)
void count_kernel(const int* __restrict__ ei, int* __restrict__ cnt) {
    int e = blockIdx.x * 256 + threadIdx.x;
    if (e >= NE) return;
    atomicAdd(&cnt[ei[NE + e]], 1);
}

__global__ __launch_bounds__(256)
void scan1_kernel(const int* __restrict__ cnt, int* __restrict__ row_ptr,
                  int* __restrict__ partials) {
    int i = blockIdx.x * 256 + threadIdx.x;
    int v = (i < NN) ? cnt[i] : 0;
    __shared__ int s[256];
    s[threadIdx.x] = v;
    __syncthreads();
#pragma unroll
    for (int off = 1; off < 256; off <<= 1) {
        int add = (threadIdx.x >= off) ? s[threadIdx.x - off] : 0;
        __syncthreads();
        s[threadIdx.x] += add;
        __syncthreads();
    }
    if (i < NN) row_ptr[i] = s[threadIdx.x] - v;  // exclusive
    if (threadIdx.x == 255) partials[blockIdx.x] = s[255];
}

__global__ __launch_bounds__(256)
void scan2_kernel(int* __restrict__ partials, int* __restrict__ poffs) {
    int v = (threadIdx.x < SCAN_BLOCKS) ? partials[threadIdx.x] : 0;
    __shared__ int s[256];
    s[threadIdx.x] = v;
    __syncthreads();
#pragma unroll
    for (int off = 1; off < 256; off <<= 1) {
        int add = (threadIdx.x >= off) ? s[threadIdx.x - off] : 0;
        __syncthreads();
        s[threadIdx.x] += add;
        __syncthreads();
    }
    poffs[threadIdx.x] = s[threadIdx.x] - v;  // exclusive
}

__global__ __launch_bounds__(256)
void scan3_kernel(int* __restrict__ row_ptr, const int* __restrict__ poffs,
                  int* __restrict__ cursor) {
    int i = blockIdx.x * 256 + threadIdx.x;
    if (i < NN) {
        int v = row_ptr[i] + poffs[blockIdx.x];
        row_ptr[i] = v;
        cursor[i] = v;
    }
    if (i == 0) row_ptr[NN] = NE;
}

__global__ __launch_bounds__(256)
void place_kernel(const int* __restrict__ ei, int* __restrict__ cursor,
                  int* __restrict__ csr) {
    int e = blockIdx.x * 256 + threadIdx.x;
    if (e >= NE) return;
    int pos = atomicAdd(&cursor[ei[NE + e]], 1);
    csr[pos] = ei[e];
}

// ---------------------------------------------------------------------------
// fp32 -> bf16 table conversion.
// ---------------------------------------------------------------------------
__global__ __launch_bounds__(256)
void x2bf_kernel(const float* __restrict__ x, __hip_bfloat16* __restrict__ xb) {
    int i4 = blockIdx.x * 256 + threadIdx.x;
    if (i4 >= NN * HD / 4) return;
    float4 v = *(const float4*)(x + (size_t)i4 * 4);
    union { ushort4 u; __hip_bfloat16 b[4]; } p;
    p.b[0] = __float2bfloat16(v.x);
    p.b[1] = __float2bfloat16(v.y);
    p.b[2] = __float2bfloat16(v.z);
    p.b[3] = __float2bfloat16(v.w);
    *(ushort4*)((unsigned short*)xb + (size_t)i4 * 4) = p.u;
}

// ---------------------------------------------------------------------------
// Aggregation: one wave per dst row. h[r] = x_f32[r] + sum_nb bf16(x)[nb].
// ---------------------------------------------------------------------------
__global__ __launch_bounds__(256)
void agg_kernel(const float* __restrict__ x, const __hip_bfloat16* __restrict__ xb,
                const int* __restrict__ row_ptr, const int* __restrict__ csr,
                float* __restrict__ h) {
    int row = blockIdx.x * 4 + (threadIdx.x >> 6);
    int lane = threadIdx.x & 63;
    int s = row_ptr[row], e = row_ptr[row + 1];
    int cnt = e - s;
    int ids = (lane < cnt) ? csr[s + lane] : 0;
    float acc = x[(size_t)row * HD + lane];
    int m = min(cnt, 64);
    for (int j = 0; j < m; j++) {
        int nb = __shfl(ids, j);
        acc += __bfloat162float(xb[(size_t)nb * HD + lane]);
    }
    for (int j = s + 64; j < e; j++) {  // degree > 64 fallback
        acc += __bfloat162float(xb[(size_t)csr[j] * HD + lane]);
    }
    h[(size_t)row * HD + lane] = acc;
}

// ---------------------------------------------------------------------------
// Fused MLP + BN-stats epilogue. hout = ReLU(hin @ W1 + b1) @ W2 + b2.
// Block = 128 rows x 256 threads (4 waves). Wave wv owns cols [wv*16,+16);
// thread handles rows lane and lane+64 (2 rows -> 32 FMA per 4 W-broadcasts).
// One LDS tile sh[128*65] is reused: input -> t (post-GEMM1) -> output, with
// barriers at each phase boundary. W staged in sW (W1 then W2).
// ---------------------------------------------------------------------------
__global__ __launch_bounds__(256)
void mlp_kernel(const float* __restrict__ hin, float* __restrict__ hout,
                const float* __restrict__ W1, const float* __restrict__ b1,
                const float* __restrict__ W2, const float* __restrict__ b2,
                float* __restrict__ stats) {
    __shared__ float sh[128 * 65];
    __shared__ float sW[64 * 64];
    __shared__ float sb[64];
    __shared__ float red[2][4][64];
    int tid = threadIdx.x;
    int base = blockIdx.x * 128;

    for (int i = tid; i < 4096; i += 256) sW[i] = W1[i];
    if (tid < 64) sb[tid] = b1[tid];
    // stage 128 rows: float4 global reads, scalar LDS writes (65-stride)
#pragma unroll
    for (int i = 0; i < 8; i++) {
        int i4 = tid + 256 * i;          // 0..2047 float4s
        int row = i4 >> 4, col = (i4 & 15) * 4;
        int grow = base + row;
        float4 v = (grow < NN) ? *(const float4*)(hin + (size_t)grow * HD + col)
                               : make_float4(0.f, 0.f, 0.f, 0.f);
        float* d = sh + row * 65 + col;
        d[0] = v.x; d[1] = v.y; d[2] = v.z; d[3] = v.w;
    }
    __syncthreads();

    int wv = tid >> 6;
    int lane = tid & 63;

    float acc0[16], acc1[16];
    // ---- GEMM1 ----
#pragma unroll
    for (int j = 0; j < 16; j++) { acc0[j] = sb[wv * 16 + j]; acc1[j] = acc0[j]; }
    for (int k = 0; k < 64; k++) {
        float a0 = sh[lane * 65 + k];
        float a1 = sh[(64 + lane) * 65 + k];
        const float4* wr = (const float4*)(sW + k * 64 + wv * 16);
#pragma unroll
        for (int q = 0; q < 4; q++) {
            float4 w = wr[q];
            acc0[4 * q + 0] = fmaf(a0, w.x, acc0[4 * q + 0]);
            acc0[4 * q + 1] = fmaf(a0, w.y, acc0[4 * q + 1]);
            acc0[4 * q + 2] = fmaf(a0, w.z, acc0[4 * q + 2]);
            acc0[4 * q + 3] = fmaf(a0, w.w, acc0[4 * q + 3]);
            acc1[4 * q + 0] = fmaf(a1, w.x, acc1[4 * q + 0]);
            acc1[4 * q + 1] = fmaf(a1, w.y, acc1[4 * q + 1]);
            acc1[4 * q + 2] = fmaf(a1, w.z, acc1[4 * q + 2]);
            acc1[4 * q + 3] = fmaf(a1, w.w, acc1[4 * q + 3]);
        }
    }
    __syncthreads();  // all input reads of sh + W1 reads of sW complete

    // t = ReLU(acc) overwrites sh; restage W2/b2
#pragma unroll
    for (int j = 0; j < 16; j++) {
        sh[lane * 65 + wv * 16 + j] = fmaxf(acc0[j], 0.f);
        sh[(64 + lane) * 65 + wv * 16 + j] = fmaxf(acc1[j], 0.f);
    }
    for (int i = tid; i < 4096; i += 256) sW[i] = W2[i];
    if (tid < 64) sb[tid] = b2[tid];
    __syncthreads();

    // ---- GEMM2 ----
#pragma unroll
    for (int j = 0; j < 16; j++) { acc0[j] = sb[wv * 16 + j]; acc1[j] = acc0[j]; }
    for (int k = 0; k < 64; k++) {
        float a0 = sh[lane * 65 + k];
        float a1 = sh[(64 + lane) * 65 + k];
        const float4* wr = (const float4*)(sW + k * 64 + wv * 16);
#pragma unroll
        for (int q = 0; q < 4; q++) {
            float4 w = wr[q];
            acc0[4 * q + 0] = fmaf(a0, w.x, acc0[4 * q + 0]);
            acc0[4 * q + 1] = fmaf(a0, w.y, acc0[4 * q + 1]);
            acc0[4 * q + 2] = fmaf(a0, w.z, acc0[4 * q + 2]);
            acc0[4 * q + 3] = fmaf(a0, w.w, acc0[4 * q + 3]);
            acc1[4 * q + 0] = fmaf(a1, w.x, acc1[4 * q + 0]);
            acc1[4 * q + 1] = fmaf(a1, w.y, acc1[4 * q + 1]);
            acc1[4 * q + 2] = fmaf(a1, w.z, acc1[4 * q + 2]);
            acc1[4 * q + 3] = fmaf(a1, w.w, acc1[4 * q + 3]);
        }
    }
    __syncthreads();  // all t reads complete before overwrite
#pragma unroll
    for (int j = 0; j < 16; j++) {
        sh[lane * 65 + wv * 16 + j] = acc0[j];
        sh[(64 + lane) * 65 + wv * 16 + j] = acc1[j];
    }
    __syncthreads();

    // coalesced store (float4)
#pragma unroll
    for (int i = 0; i < 8; i++) {
        int i4 = tid + 256 * i;
        int row = i4 >> 4, col = (i4 & 15) * 4;
        int grow = base + row;
        if (grow < NN) {
            const float* s = sh + row * 65 + col;
            *(float4*)(hout + (size_t)grow * HD + col) =
                make_float4(s[0], s[1], s[2], s[3]);
        }
    }

    // ---- fused BN-stats partials over the output tile ----
    {
        int col = tid & 63;
        int r0 = (tid >> 6) * 32;
        float s = 0.f, ss = 0.f;
#pragma unroll
        for (int r = 0; r < 32; r++) {
            float v = (base + r0 + r < NN) ? sh[(r0 + r) * 65 + col] : 0.f;
            s += v;
            ss += v * v;
        }
        red[0][tid >> 6][col] = s;
        red[1][tid >> 6][col] = ss;
        __syncthreads();
        if (tid < 64) {
            float S = red[0][0][col] + red[0][1][col] + red[0][2][col] + red[0][3][col];
            atomicAdd(stats + col, S);
        } else if (tid < 128) {
            float SS = red[1][0][col] + red[1][1][col] + red[1][2][col] + red[1][3][col];
            atomicAdd(stats + 64 + col, SS);
        }
    }
}

// ---------------------------------------------------------------------------
// BatchNorm (batch stats, biased var) + affine + ReLU. In-place fp32 +
// dual-write bf16 copy (gather table for the next layer's agg).
// ---------------------------------------------------------------------------
__global__ __launch_bounds__(256)
void norm_kernel(float* h, const float* __restrict__ stats,
                 const float* __restrict__ g, const float* __restrict__ be,
                 __hip_bfloat16* __restrict__ xb) {
    size_t i4 = (size_t)blockIdx.x * 256 + threadIdx.x;
    if (i4 >= (size_t)NN * HD / 4) return;
    size_t off = i4 * 4;
    int col = (int)(off & 63);
    float4 v = *(const float4*)(h + off);
    float4 sm = *(const float4*)(stats + col);
    float4 sq = *(const float4*)(stats + 64 + col);
    float4 gg = *(const float4*)(g + col);
    float4 bb = *(const float4*)(be + col);
    const float inv = 1.f / (float)NN;
    float4 o;
    {
        float mu = sm.x * inv, var = sq.x * inv - mu * mu;
        float sc = gg.x * rsqrtf(var + BN_EPS);
        o.x = fmaxf((v.x - mu) * sc + bb.x, 0.f);
    }
    {
        float mu = sm.y * inv, var = sq.y * inv - mu * mu;
        float sc = gg.y * rsqrtf(var + BN_EPS);
        o.y = fmaxf((v.y - mu) * sc + bb.y, 0.f);
    }
    {
        float mu = sm.z * inv, var = sq.z * inv - mu * mu;
        float sc = gg.z * rsqrtf(var + BN_EPS);
        o.z = fmaxf((v.z - mu) * sc + bb.z, 0.f);
    }
    {
        float mu = sm.w * inv, var = sq.w * inv - mu * mu;
        float sc = gg.w * rsqrtf(var + BN_EPS);
        o.w = fmaxf((v.w - mu) * sc + bb.w, 0.f);
    }
    *(float4*)(h + off) = o;
    union { ushort4 u; __hip_bfloat16 b[4]; } p;
    p.b[0] = __float2bfloat16(o.x);
    p.b[1] = __float2bfloat16(o.y);
    p.b[2] = __float2bfloat16(o.z);
    p.b[3] = __float2bfloat16(o.w);
    *(ushort4*)((unsigned short*)xb + off) = p.u;
}

// ---------------------------------------------------------------------------
// Mean pool: 200 partial blocks + tiny finalize.
// ---------------------------------------------------------------------------
__global__ __launch_bounds__(256)
void pool_partial_kernel(const float* __restrict__ x, const int* __restrict__ batch,
                         float* __restrict__ sums) {
    int col = threadIdx.x & 63;
    int rl = threadIdx.x >> 6;
    int rs = blockIdx.x * 250;
    int re = rs + 250;
    int cur = -1;
    float acc = 0.f;
    for (int r = rs + rl; r < re; r += 4) {
        int g = batch[r];
        float v = x[(size_t)r * HD + col];
        if (g != cur) {
            if (cur >= 0) atomicAdd(&sums[cur * HD + col], acc);
            cur = g;
            acc = v;
        } else {
            acc += v;
        }
    }
    if (cur >= 0) atomicAdd(&sums[cur * HD + col], acc);
}

__device__ __forceinline__ int lower_bound_batch(const int* __restrict__ b, int val) {
    int lo = 0, hi = NN;
    while (lo < hi) {
        int mid = (lo + hi) >> 1;
        if (b[mid] < val) lo = mid + 1;
        else hi = mid;
    }
    return lo;
}

__global__ __launch_bounds__(1024)
void pool_finalize_kernel(const float* __restrict__ sums, const int* __restrict__ batch,
                          float* __restrict__ out) {
    int g = threadIdx.x >> 6;
    int col = threadIdx.x & 63;
    int s = lower_bound_batch(batch, g);
    int e = lower_bound_batch(batch, g + 1);
    float cnt = (float)(e - s);
    out[g * HD + col] = sums[g * HD + col] / fmaxf(cnt, 1.f);
}

extern "C" void kernel_launch(void* const* d_in, const int* in_sizes, int n_in,
                              void* d_out, int out_size, void* d_ws, size_t ws_size,
                              hipStream_t stream) {
    const float* x = (const float*)d_in[0];
    const int* ei = (const int*)d_in[1];
    const int* batch = (const int*)d_in[2];
    const float* W1_0 = (const float*)d_in[3];
    const float* b1_0 = (const float*)d_in[4];
    const float* W2_0 = (const float*)d_in[5];
    const float* b2_0 = (const float*)d_in[6];
    const float* g_0 = (const float*)d_in[7];
    const float* be_0 = (const float*)d_in[8];
    const float* W1_1 = (const float*)d_in[9];
    const float* b1_1 = (const float*)d_in[10];
    const float* W2_1 = (const float*)d_in[11];
    const float* b2_1 = (const float*)d_in[12];
    const float* g_1 = (const float*)d_in[13];
    const float* be_1 = (const float*)d_in[14];

    float* out = (float*)d_out;  // node output; also x1 staging between layers

    // workspace layout (~23 MB)
    float* buf_h = (float*)d_ws;                       // 3.2M f32 (agg output)
    float* stats = buf_h + (size_t)NN * HD;            // 128 f32
    float* psums = stats + 128;                        // 1024 f32
    int* row_ptr = (int*)(psums + 1024);               // NN+1
    int* cnt = row_ptr + (NN + 2);                     // NN (also cursor)
    int* partials = cnt + NN;                          // 256
    int* poffs = partials + 256;                       // 256
    int* csr = poffs + 256;                            // NE
    __hip_bfloat16* xb = (__hip_bfloat16*)(csr + NE);  // 3.2M bf16 gather table

    dim3 b256(256);
    int egrid = (NE + 255) / 256;          // 3125
    int mlp_grid = (NN + 127) / 128;       // 391
    int norm_grid = (NN * HD / 4 + 255) / 256;
    int agg_grid = NN / 4;                 // 12500

    // ---- CSR build (shared by both layers) ----
    hipMemsetAsync(cnt, 0, NN * sizeof(int), stream);
    count_kernel<<<egrid, b256, 0, stream>>>(ei, cnt);
    scan1_kernel<<<SCAN_BLOCKS, b256, 0, stream>>>(cnt, row_ptr, partials);
    scan2_kernel<<<1, b256, 0, stream>>>(partials, poffs);
    scan3_kernel<<<SCAN_BLOCKS, b256, 0, stream>>>(row_ptr, poffs, cnt);
    place_kernel<<<egrid, b256, 0, stream>>>(ei, cnt, csr);

    // ---- layer 0 ----
    x2bf_kernel<<<norm_grid, b256, 0, stream>>>(x, xb);
    agg_kernel<<<agg_grid, b256, 0, stream>>>(x, xb, row_ptr, csr, buf_h);
    hipMemsetAsync(stats, 0, 128 * sizeof(float), stream);
    mlp_kernel<<<mlp_grid, b256, 0, stream>>>(buf_h, out, W1_0, b1_0, W2_0, b2_0, stats);
    norm_kernel<<<norm_grid, b256, 0, stream>>>(out, stats, g_0, be_0, xb);

    // ---- layer 1 ----
    agg_kernel<<<agg_grid, b256, 0, stream>>>(out, xb, row_ptr, csr, buf_h);
    hipMemsetAsync(stats, 0, 128 * sizeof(float), stream);
    mlp_kernel<<<mlp_grid, b256, 0, stream>>>(buf_h, out, W1_1, b1_1, W2_1, b2_1, stats);
    norm_kernel<<<norm_grid, b256, 0, stream>>>(out, stats, g_1, be_1, xb);

    // ---- pool ----
    hipMemsetAsync(psums, 0, 1024 * sizeof(float), stream);
    pool_partial_kernel<<<200, b256, 0, stream>>>(out, batch, psums);
    pool_finalize_kernel<<<1, dim3(1024), 0, stream>>>(psums, batch, out + (size_t)NN * HD);
}

// Round 7
// 330.705 us; speedup vs baseline: 5.5730x; 1.1561x over previous
//
#include <hip/hip_runtime.h>
#include <hip/hip_bf16.h>

// GIN: 2 x (CSR gather-sum + MLP(64->64->64) + BatchNorm + ReLU) + mean pool
// N=50000 nodes, E=800000 edges, H=64, G=16 graphs. fp32 in/out.
// R7: agg gather loop unrolled 4x w/ independent accumulators (R6: VGPR=8 ->
// ~1 outstanding gather, latency-bound at 51us, VALUBusy 22%). All 4 memsets
// folded into existing kernels (x2bf zeroes cnt, agg zeroes stats, mlp zeroes
// psums) -> 17 dispatches instead of 23.

constexpr int NN = 50000;
constexpr int NE = 800000;
constexpr int HD = 64;
constexpr int NG = 16;
constexpr float BN_EPS = 1e-5f;
constexpr int SCAN_BLOCKS = (NN + 255) / 256;  // 196

// ---------------------------------------------------------------------------
// CSR build: degree histogram -> exclusive scan -> edge placement.
// ---------------------------------------------------------------------------
__global__ __launch_bounds__(256)
void count_kernel(const int* __restrict__ ei, int* __restrict__ cnt) {
    int e = blockIdx.x * 256 + threadIdx.x;
    if (e >= NE) return;
    atomicAdd(&cnt[ei[NE + e]], 1);
}

__global__ __launch_bounds__(256)
void scan1_kernel(const int* __restrict__ cnt, int* __restrict__ row_ptr,
                  int* __restrict__ partials) {
    int i = blockIdx.x * 256 + threadIdx.x;
    int v = (i < NN) ? cnt[i] : 0;
    __shared__ int s[256];
    s[threadIdx.x] = v;
    __syncthreads();
#pragma unroll
    for (int off = 1; off < 256; off <<= 1) {
        int add = (threadIdx.x >= off) ? s[threadIdx.x - off] : 0;
        __syncthreads();
        s[threadIdx.x] += add;
        __syncthreads();
    }
    if (i < NN) row_ptr[i] = s[threadIdx.x] - v;  // exclusive
    if (threadIdx.x == 255) partials[blockIdx.x] = s[255];
}

__global__ __launch_bounds__(256)
void scan2_kernel(int* __restrict__ partials, int* __restrict__ poffs) {
    int v = (threadIdx.x < SCAN_BLOCKS) ? partials[threadIdx.x] : 0;
    __shared__ int s[256];
    s[threadIdx.x] = v;
    __syncthreads();
#pragma unroll
    for (int off = 1; off < 256; off <<= 1) {
        int add = (threadIdx.x >= off) ? s[threadIdx.x - off] : 0;
        __syncthreads();
        s[threadIdx.x] += add;
        __syncthreads();
    }
    poffs[threadIdx.x] = s[threadIdx.x] - v;  // exclusive
}

__global__ __launch_bounds__(256)
void scan3_kernel(int* __restrict__ row_ptr, const int* __restrict__ poffs,
                  int* __restrict__ cursor) {
    int i = blockIdx.x * 256 + threadIdx.x;
    if (i < NN) {
        int v = row_ptr[i] + poffs[blockIdx.x];
        row_ptr[i] = v;
        cursor[i] = v;
    }
    if (i == 0) row_ptr[NN] = NE;
}

__global__ __launch_bounds__(256)
void place_kernel(const int* __restrict__ ei, int* __restrict__ cursor,
                  int* __restrict__ csr) {
    int e = blockIdx.x * 256 + threadIdx.x;
    if (e >= NE) return;
    int pos = atomicAdd(&cursor[ei[NE + e]], 1);
    csr[pos] = ei[e];
}

// ---------------------------------------------------------------------------
// fp32 -> bf16 table conversion. Also zeroes cnt[] for the following
// count_kernel (stream order guarantees completion first).
// ---------------------------------------------------------------------------
__global__ __launch_bounds__(256)
void x2bf_kernel(const float* __restrict__ x, __hip_bfloat16* __restrict__ xb,
                 int* __restrict__ cnt) {
    int i4 = blockIdx.x * 256 + threadIdx.x;
    if (i4 < NN) cnt[i4] = 0;
    if (i4 >= NN * HD / 4) return;
    float4 v = *(const float4*)(x + (size_t)i4 * 4);
    union { ushort4 u; __hip_bfloat16 b[4]; } p;
    p.b[0] = __float2bfloat16(v.x);
    p.b[1] = __float2bfloat16(v.y);
    p.b[2] = __float2bfloat16(v.z);
    p.b[3] = __float2bfloat16(v.w);
    *(ushort4*)((unsigned short*)xb + (size_t)i4 * 4) = p.u;
}

// ---------------------------------------------------------------------------
// Aggregation: one wave per dst row. h[r] = x_f32[r] + sum_nb bf16(x)[nb].
// Gather loop unrolled 4x (4 independent outstanding loads). Block 0 zeroes
// stats for the following mlp_kernel (stats untouched during agg).
// ---------------------------------------------------------------------------
__global__ __launch_bounds__(256)
void agg_kernel(const float* __restrict__ x, const __hip_bfloat16* __restrict__ xb,
                const int* __restrict__ row_ptr, const int* __restrict__ csr,
                float* __restrict__ h, float* __restrict__ stats) {
    if (blockIdx.x == 0 && threadIdx.x < 128) stats[threadIdx.x] = 0.f;
    int row = blockIdx.x * 4 + (threadIdx.x >> 6);
    int lane = threadIdx.x & 63;
    int s = row_ptr[row], e = row_ptr[row + 1];
    int cnt = e - s;
    int ids = (lane < cnt) ? csr[s + lane] : 0;
    float acc = x[(size_t)row * HD + lane];
    int m = min(cnt, 64);
    int j = 0;
    float a0 = 0.f, a1 = 0.f, a2 = 0.f, a3 = 0.f;
    for (; j + 4 <= m; j += 4) {
        int nb0 = __shfl(ids, j);
        int nb1 = __shfl(ids, j + 1);
        int nb2 = __shfl(ids, j + 2);
        int nb3 = __shfl(ids, j + 3);
        float v0 = __bfloat162float(xb[(size_t)nb0 * HD + lane]);
        float v1 = __bfloat162float(xb[(size_t)nb1 * HD + lane]);
        float v2 = __bfloat162float(xb[(size_t)nb2 * HD + lane]);
        float v3 = __bfloat162float(xb[(size_t)nb3 * HD + lane]);
        a0 += v0; a1 += v1; a2 += v2; a3 += v3;
    }
    acc += (a0 + a1) + (a2 + a3);
    for (; j < m; j++) {
        int nb = __shfl(ids, j);
        acc += __bfloat162float(xb[(size_t)nb * HD + lane]);
    }
    for (int jj = s + 64; jj < e; jj++) {  // degree > 64 fallback
        acc += __bfloat162float(xb[(size_t)csr[jj] * HD + lane]);
    }
    h[(size_t)row * HD + lane] = acc;
}

// ---------------------------------------------------------------------------
// Fused MLP + BN-stats epilogue. hout = ReLU(hin @ W1 + b1) @ W2 + b2.
// Block = 128 rows x 256 threads; wave wv owns cols [wv*16,+16); thread does
// rows lane and lane+64. One LDS tile reused input->t->output (barriered).
// Block 0 zeroes psums (only touched by pool kernels, 2 dispatches later).
// ---------------------------------------------------------------------------
__global__ __launch_bounds__(256)
void mlp_kernel(const float* __restrict__ hin, float* __restrict__ hout,
                const float* __restrict__ W1, const float* __restrict__ b1,
                const float* __restrict__ W2, const float* __restrict__ b2,
                float* __restrict__ stats, float* __restrict__ psums) {
    __shared__ float sh[128 * 65];
    __shared__ float sW[64 * 64];
    __shared__ float sb[64];
    __shared__ float red[2][4][64];
    int tid = threadIdx.x;
    int base = blockIdx.x * 128;

    if (blockIdx.x == 0) {
        float4 z = make_float4(0.f, 0.f, 0.f, 0.f);
        *(float4*)(psums + tid * 4) = z;
    }
    for (int i = tid; i < 4096; i += 256) sW[i] = W1[i];
    if (tid < 64) sb[tid] = b1[tid];
#pragma unroll
    for (int i = 0; i < 8; i++) {
        int i4 = tid + 256 * i;          // 0..2047 float4s
        int row = i4 >> 4, col = (i4 & 15) * 4;
        int grow = base + row;
        float4 v = (grow < NN) ? *(const float4*)(hin + (size_t)grow * HD + col)
                               : make_float4(0.f, 0.f, 0.f, 0.f);
        float* d = sh + row * 65 + col;
        d[0] = v.x; d[1] = v.y; d[2] = v.z; d[3] = v.w;
    }
    __syncthreads();

    int wv = tid >> 6;
    int lane = tid & 63;

    float acc0[16], acc1[16];
    // ---- GEMM1 ----
#pragma unroll
    for (int j = 0; j < 16; j++) { acc0[j] = sb[wv * 16 + j]; acc1[j] = acc0[j]; }
    for (int k = 0; k < 64; k++) {
        float a0 = sh[lane * 65 + k];
        float a1 = sh[(64 + lane) * 65 + k];
        const float4* wr = (const float4*)(sW + k * 64 + wv * 16);
#pragma unroll
        for (int q = 0; q < 4; q++) {
            float4 w = wr[q];
            acc0[4 * q + 0] = fmaf(a0, w.x, acc0[4 * q + 0]);
            acc0[4 * q + 1] = fmaf(a0, w.y, acc0[4 * q + 1]);
            acc0[4 * q + 2] = fmaf(a0, w.z, acc0[4 * q + 2]);
            acc0[4 * q + 3] = fmaf(a0, w.w, acc0[4 * q + 3]);
            acc1[4 * q + 0] = fmaf(a1, w.x, acc1[4 * q + 0]);
            acc1[4 * q + 1] = fmaf(a1, w.y, acc1[4 * q + 1]);
            acc1[4 * q + 2] = fmaf(a1, w.z, acc1[4 * q + 2]);
            acc1[4 * q + 3] = fmaf(a1, w.w, acc1[4 * q + 3]);
        }
    }
    __syncthreads();  // all input reads of sh + W1 reads of sW complete

    // t = ReLU(acc) overwrites sh; restage W2/b2
#pragma unroll
    for (int j = 0; j < 16; j++) {
        sh[lane * 65 + wv * 16 + j] = fmaxf(acc0[j], 0.f);
        sh[(64 + lane) * 65 + wv * 16 + j] = fmaxf(acc1[j], 0.f);
    }
    for (int i = tid; i < 4096; i += 256) sW[i] = W2[i];
    if (tid < 64) sb[tid] = b2[tid];
    __syncthreads();

    // ---- GEMM2 ----
#pragma unroll
    for (int j = 0; j < 16; j++) { acc0[j] = sb[wv * 16 + j]; acc1[j] = acc0[j]; }
    for (int k = 0; k < 64; k++) {
        float a0 = sh[lane * 65 + k];
        float a1 = sh[(64 + lane) * 65 + k];
        const float4* wr = (const float4*)(sW + k * 64 + wv * 16);
#pragma unroll
        for (int q = 0; q < 4; q++) {
            float4 w = wr[q];
            acc0[4 * q + 0] = fmaf(a0, w.x, acc0[4 * q + 0]);
            acc0[4 * q + 1] = fmaf(a0, w.y, acc0[4 * q + 1]);
            acc0[4 * q + 2] = fmaf(a0, w.z, acc0[4 * q + 2]);
            acc0[4 * q + 3] = fmaf(a0, w.w, acc0[4 * q + 3]);
            acc1[4 * q + 0] = fmaf(a1, w.x, acc1[4 * q + 0]);
            acc1[4 * q + 1] = fmaf(a1, w.y, acc1[4 * q + 1]);
            acc1[4 * q + 2] = fmaf(a1, w.z, acc1[4 * q + 2]);
            acc1[4 * q + 3] = fmaf(a1, w.w, acc1[4 * q + 3]);
        }
    }
    __syncthreads();  // all t reads complete before overwrite
#pragma unroll
    for (int j = 0; j < 16; j++) {
        sh[lane * 65 + wv * 16 + j] = acc0[j];
        sh[(64 + lane) * 65 + wv * 16 + j] = acc1[j];
    }
    __syncthreads();

    // coalesced store (float4)
#pragma unroll
    for (int i = 0; i < 8; i++) {
        int i4 = tid + 256 * i;
        int row = i4 >> 4, col = (i4 & 15) * 4;
        int grow = base + row;
        if (grow < NN) {
            const float* s = sh + row * 65 + col;
            *(float4*)(hout + (size_t)grow * HD + col) =
                make_float4(s[0], s[1], s[2], s[3]);
        }
    }

    // ---- fused BN-stats partials over the output tile ----
    {
        int col = tid & 63;
        int r0 = (tid >> 6) * 32;
        float s = 0.f, ss = 0.f;
#pragma unroll
        for (int r = 0; r < 32; r++) {
            float v = (base + r0 + r < NN) ? sh[(r0 + r) * 65 + col] : 0.f;
            s += v;
            ss += v * v;
        }
        red[0][tid >> 6][col] = s;
        red[1][tid >> 6][col] = ss;
        __syncthreads();
        if (tid < 64) {
            float S = red[0][0][col] + red[0][1][col] + red[0][2][col] + red[0][3][col];
            atomicAdd(stats + col, S);
        } else if (tid < 128) {
            float SS = red[1][0][col] + red[1][1][col] + red[1][2][col] + red[1][3][col];
            atomicAdd(stats + 64 + col, SS);
        }
    }
}

// ---------------------------------------------------------------------------
// BatchNorm (batch stats, biased var) + affine + ReLU. In-place fp32 +
// dual-write bf16 copy (gather table for the next layer's agg).
// ---------------------------------------------------------------------------
__global__ __launch_bounds__(256)
void norm_kernel(float* h, const float* __restrict__ stats,
                 const float* __restrict__ g, const float* __restrict__ be,
                 __hip_bfloat16* __restrict__ xb) {
    size_t i4 = (size_t)blockIdx.x * 256 + threadIdx.x;
    if (i4 >= (size_t)NN * HD / 4) return;
    size_t off = i4 * 4;
    int col = (int)(off & 63);
    float4 v = *(const float4*)(h + off);
    float4 sm = *(const float4*)(stats + col);
    float4 sq = *(const float4*)(stats + 64 + col);
    float4 gg = *(const float4*)(g + col);
    float4 bb = *(const float4*)(be + col);
    const float inv = 1.f / (float)NN;
    float4 o;
    {
        float mu = sm.x * inv, var = sq.x * inv - mu * mu;
        float sc = gg.x * rsqrtf(var + BN_EPS);
        o.x = fmaxf((v.x - mu) * sc + bb.x, 0.f);
    }
    {
        float mu = sm.y * inv, var = sq.y * inv - mu * mu;
        float sc = gg.y * rsqrtf(var + BN_EPS);
        o.y = fmaxf((v.y - mu) * sc + bb.y, 0.f);
    }
    {
        float mu = sm.z * inv, var = sq.z * inv - mu * mu;
        float sc = gg.z * rsqrtf(var + BN_EPS);
        o.z = fmaxf((v.z - mu) * sc + bb.z, 0.f);
    }
    {
        float mu = sm.w * inv, var = sq.w * inv - mu * mu;
        float sc = gg.w * rsqrtf(var + BN_EPS);
        o.w = fmaxf((v.w - mu) * sc + bb.w, 0.f);
    }
    *(float4*)(h + off) = o;
    union { ushort4 u; __hip_bfloat16 b[4]; } p;
    p.b[0] = __float2bfloat16(o.x);
    p.b[1] = __float2bfloat16(o.y);
    p.b[2] = __float2bfloat16(o.z);
    p.b[3] = __float2bfloat16(o.w);
    *(ushort4*)((unsigned short*)xb + off) = p.u;
}

// ---------------------------------------------------------------------------
// Mean pool: 200 partial blocks + tiny finalize.
// ---------------------------------------------------------------------------
__global__ __launch_bounds__(256)
void pool_partial_kernel(const float* __restrict__ x, const int* __restrict__ batch,
                         float* __restrict__ sums) {
    int col = threadIdx.x & 63;
    int rl = threadIdx.x >> 6;
    int rs = blockIdx.x * 250;
    int re = rs + 250;
    int cur = -1;
    float acc = 0.f;
    for (int r = rs + rl; r < re; r += 4) {
        int g = batch[r];
        float v = x[(size_t)r * HD + col];
        if (g != cur) {
            if (cur >= 0) atomicAdd(&sums[cur * HD + col], acc);
            cur = g;
            acc = v;
        } else {
            acc += v;
        }
    }
    if (cur >= 0) atomicAdd(&sums[cur * HD + col], acc);
}

__device__ __forceinline__ int lower_bound_batch(const int* __restrict__ b, int val) {
    int lo = 0, hi = NN;
    while (lo < hi) {
        int mid = (lo + hi) >> 1;
        if (b[mid] < val) lo = mid + 1;
        else hi = mid;
    }
    return lo;
}

__global__ __launch_bounds__(1024)
void pool_finalize_kernel(const float* __restrict__ sums, const int* __restrict__ batch,
                          float* __restrict__ out) {
    int g = threadIdx.x >> 6;
    int col = threadIdx.x & 63;
    int s = lower_bound_batch(batch, g);
    int e = lower_bound_batch(batch, g + 1);
    float cnt = (float)(e - s);
    out[g * HD + col] = sums[g * HD + col] / fmaxf(cnt, 1.f);
}

extern "C" void kernel_launch(void* const* d_in, const int* in_sizes, int n_in,
                              void* d_out, int out_size, void* d_ws, size_t ws_size,
                              hipStream_t stream) {
    const float* x = (const float*)d_in[0];
    const int* ei = (const int*)d_in[1];
    const int* batch = (const int*)d_in[2];
    const float* W1_0 = (const float*)d_in[3];
    const float* b1_0 = (const float*)d_in[4];
    const float* W2_0 = (const float*)d_in[5];
    const float* b2_0 = (const float*)d_in[6];
    const float* g_0 = (const float*)d_in[7];
    const float* be_0 = (const float*)d_in[8];
    const float* W1_1 = (const float*)d_in[9];
    const float* b1_1 = (const float*)d_in[10];
    const float* W2_1 = (const float*)d_in[11];
    const float* b2_1 = (const float*)d_in[12];
    const float* g_1 = (const float*)d_in[13];
    const float* be_1 = (const float*)d_in[14];

    float* out = (float*)d_out;  // node output; also x1 staging between layers

    // workspace layout (~23 MB)
    float* buf_h = (float*)d_ws;                       // 3.2M f32 (agg output)
    float* stats = buf_h + (size_t)NN * HD;            // 128 f32
    float* psums = stats + 128;                        // 1024 f32
    int* row_ptr = (int*)(psums + 1024);               // NN+1
    int* cnt = row_ptr + (NN + 2);                     // NN (also cursor)
    int* partials = cnt + NN;                          // 256
    int* poffs = partials + 256;                       // 256
    int* csr = poffs + 256;                            // NE
    __hip_bfloat16* xb = (__hip_bfloat16*)(csr + NE);  // 3.2M bf16 gather table

    dim3 b256(256);
    int egrid = (NE + 255) / 256;          // 3125
    int mlp_grid = (NN + 127) / 128;       // 391
    int norm_grid = (NN * HD / 4 + 255) / 256;
    int agg_grid = NN / 4;                 // 12500

    // ---- x->bf16 table + cnt zeroing, then CSR build ----
    x2bf_kernel<<<norm_grid, b256, 0, stream>>>(x, xb, cnt);
    count_kernel<<<egrid, b256, 0, stream>>>(ei, cnt);
    scan1_kernel<<<SCAN_BLOCKS, b256, 0, stream>>>(cnt, row_ptr, partials);
    scan2_kernel<<<1, b256, 0, stream>>>(partials, poffs);
    scan3_kernel<<<SCAN_BLOCKS, b256, 0, stream>>>(row_ptr, poffs, cnt);
    place_kernel<<<egrid, b256, 0, stream>>>(ei, cnt, csr);

    // ---- layer 0 ----
    agg_kernel<<<agg_grid, b256, 0, stream>>>(x, xb, row_ptr, csr, buf_h, stats);
    mlp_kernel<<<mlp_grid, b256, 0, stream>>>(buf_h, out, W1_0, b1_0, W2_0, b2_0, stats, psums);
    norm_kernel<<<norm_grid, b256, 0, stream>>>(out, stats, g_0, be_0, xb);

    // ---- layer 1 ----
    agg_kernel<<<agg_grid, b256, 0, stream>>>(out, xb, row_ptr, csr, buf_h, stats);
    mlp_kernel<<<mlp_grid, b256, 0, stream>>>(buf_h, out, W1_1, b1_1, W2_1, b2_1, stats, psums);
    norm_kernel<<<norm_grid, b256, 0, stream>>>(out, stats, g_1, be_1, xb);

    // ---- pool ----
    pool_partial_kernel<<<200, b256, 0, stream>>>(out, batch, psums);
    pool_finalize_kernel<<<1, dim3(1024), 0, stream>>>(psums, batch, out + (size_t)NN * HD);
}